// Round 5
// baseline (646.578 us; speedup 1.0000x reference)
//
#include <hip/hip_runtime.h>

// MambaTower: B=2, L=2048, E=1024, NL=2, DI=2048, DS=16, DC=4, DTR=64
#define B_   2
#define L_   2048
#define E_   1024
#define NL_  2
#define DI_  2048
#define DS_  16
#define DC_  4
#define DTR_ 64
#define NXD_ 96            // DTR + 2*DS
#define M_   (B_ * L_)     // 4096 rows
#define NCH_ 32            // scan chunks
#define LC_  64            // timesteps per chunk

typedef __attribute__((ext_vector_type(8))) short bf16x8;
typedef __attribute__((ext_vector_type(4))) float f32x4;

__device__ __forceinline__ float bf2f(unsigned short u) {
    return __uint_as_float(((unsigned)u) << 16);
}
__device__ __forceinline__ unsigned short f2bf(float f) {
    unsigned u = __float_as_uint(f);
    u += 0x7fff + ((u >> 16) & 1);
    return (unsigned short)(u >> 16);
}

#define LOG2E_ 1.44269504f
#define LN2_   0.69314718f

// hardware-transcendental forms: v_exp_f32 computes 2^x, v_log_f32 computes log2(x)
__device__ __forceinline__ float sigmoidf_(float x) {
    return __builtin_amdgcn_rcpf(1.f + __builtin_amdgcn_exp2f(-x * LOG2E_));
}
__device__ __forceinline__ float softplusf_(float x) {
    float e = __builtin_amdgcn_exp2f(x * LOG2E_);
    float s = LN2_ * __builtin_amdgcn_logf(1.f + e);
    return x > 15.f ? x : s;
}
__device__ __forceinline__ float expf_(float x) {       // e^x
    return __builtin_amdgcn_exp2f(x * LOG2E_);
}
__device__ __forceinline__ float ldin(const void* p, size_t i, int isbf) {
    return isbf ? bf2f(((const unsigned short*)p)[i]) : ((const float*)p)[i];
}
__device__ __forceinline__ void gld_lds16(const unsigned short* g, unsigned short* l) {
    __builtin_amdgcn_global_load_lds(
        (const __attribute__((address_space(1))) unsigned int*)g,
        (__attribute__((address_space(3))) unsigned int*)l, 16, 0, 0);
}
// opaque LDS read (compiler can't alias with global_load_lds; paired with
// explicit lgkmcnt(0)+sched_barrier before use)
__device__ __forceinline__ bf16x8 ds_read128_(unsigned byteoff) {
    bf16x8 r;
    asm volatile("ds_read_b128 %0, %1" : "=&v"(r) : "v"(byteoff));
    return r;
}

// build e[n] = exp(dv*a[n]) given a2[n] = a[n]*log2e; fast path uses
// a[n] = (n+1)*a[0] (validated by chk_alog) -> 1 exp + 15 muls
__device__ __forceinline__ void expvec(int fast, float dv, const float* a2, float* e) {
    if (fast) {
        float p1 = __builtin_amdgcn_exp2f(dv * a2[0]);
        float p2 = p1 * p1, p4 = p2 * p2, p8 = p4 * p4;
        e[0] = p1;        e[1] = p2;        e[2] = p2 * p1;   e[3] = p4;
        e[4] = p4 * p1;   e[5] = p4 * p2;   e[6] = e[5] * p1; e[7] = p8;
        e[8] = p8 * p1;   e[9] = p8 * p2;   e[10] = e[9] * p1; e[11] = p8 * p4;
        e[12] = e[11] * p1; e[13] = e[11] * p2; e[14] = e[13] * p1; e[15] = p8 * p8;
    } else {
#pragma unroll
        for (int n = 0; n < 16; ++n) e[n] = __builtin_amdgcn_exp2f(dv * a2[n]);
    }
}

// flags[0]=dtype(1=bf16), flags[1+layer]=A_log linear-structure fast flag
__global__ __launch_bounds__(256) void detect_kernel(const unsigned* __restrict__ x,
                                                     int* __restrict__ flags)
{
    __shared__ int cnt;
    if (threadIdx.x == 0) cnt = 0;
    __syncthreads();
    unsigned v = x[threadIdx.x];
    int e = (v >> 7) & 0xFF;
    if (e >= 90 && e <= 140) atomicAdd(&cnt, 1);
    __syncthreads();
    if (threadIdx.x == 0) {
        flags[0] = (cnt >= 192) ? 1 : 0;
        flags[1] = 1;
        flags[2] = 1;
    }
}

// validate a[n] ~= (n+1)*a[0] for every (layer,d); clear fast flag on fail
__global__ __launch_bounds__(256) void chk_alog(
    const void* __restrict__ alog, int* __restrict__ flags)
{
    int isbf = flags[0];
    int i = blockIdx.x * 256 + threadIdx.x;      // NL*DI*DS
    int layer = i / (DI_ * DS_);
    int n = i & (DS_ - 1);
    float a  = -expf_(ldin(alog, i, isbf));
    float a0 = -expf_(ldin(alog, i - n, isbf));
    float want = (n + 1) * a0;
    if (fabsf(a - want) > 0.02f * fabsf(want))
        atomicAnd(&flags[1 + layer], 0);
}

// convert weights to bf16 into wbuf (xw padded 96->128 rows). When input is
// already bf16 the in/dt/ow copies are identity -> consumers read the input
// tensors directly and we only build the padded xw block here.
#define WB_IN_  0
#define WB_XW_  4194304
#define WB_DTW_ 4456448
#define WB_OW_  4587520
#define WB_TOT_ 6684672
__global__ __launch_bounds__(256) void cvt_layer_kernel(
    const void* __restrict__ inw, const void* __restrict__ xw,
    const void* __restrict__ dtw, const void* __restrict__ ow,
    int layer, unsigned short* __restrict__ wbuf, const int* __restrict__ flag)
{
    int isbf = *flag;
    int i = blockIdx.x * 256 + threadIdx.x;    // 0..WB_TOT_-1
    if (isbf && (i < WB_XW_ || i >= WB_DTW_)) return;   // identity regions skipped
    unsigned short v;
    if (i < WB_XW_) {
        v = isbf ? ((const unsigned short*)inw)[(size_t)layer * 2 * DI_ * E_ + i]
                 : f2bf(((const float*)inw)[(size_t)layer * 2 * DI_ * E_ + i]);
    } else if (i < WB_DTW_) {
        int j = i - WB_XW_; int r = j >> 11, k = j & (DI_ - 1);
        v = (r < NXD_)
          ? (isbf ? ((const unsigned short*)xw)[(size_t)layer * NXD_ * DI_ + (size_t)r * DI_ + k]
                  : f2bf(((const float*)xw)[(size_t)layer * NXD_ * DI_ + (size_t)r * DI_ + k]))
          : (unsigned short)0;
    } else if (i < WB_OW_) {
        int j = i - WB_DTW_;
        v = isbf ? ((const unsigned short*)dtw)[(size_t)layer * DI_ * DTR_ + j]
                 : f2bf(((const float*)dtw)[(size_t)layer * DI_ * DTR_ + j]);
    } else {
        int j = i - WB_OW_;
        v = isbf ? ((const unsigned short*)ow)[(size_t)layer * E_ * DI_ + j]
                 : f2bf(((const float*)ow)[(size_t)layer * E_ * DI_ + j]);
    }
    wbuf[i] = v;
}

// h = x + pos (fp32 + bf16 copies)
__global__ __launch_bounds__(256) void add_pos_kernel(
    const void* __restrict__ x, const void* __restrict__ pos,
    float* __restrict__ h, unsigned short* __restrict__ h16,
    const int* __restrict__ flag)
{
    int isbf = *flag;
    int i = blockIdx.x * 256 + threadIdx.x;
    float v = ldin(x, i, isbf) + ldin(pos, i & (L_ * E_ - 1), isbf);
    h[i] = v;
    h16[i] = f2bf(v);
}

// ---- MFMA GEMM: C[M,N] = A[M,K](bf16) * W[N,K](bf16)^T ----
// 128x128 tile, BK=64, 256 threads = 4 waves (2x2 of 64x64).
// XOR-swizzled LDS chunk layout (0 bank conflicts, coalesced staging).
// ep: 0=fp32 store, 2=softplus(v+bias[n]) -> bf16 store
// Worig: when non-null and *flag (bf16 inputs), use original weight tensor.
__global__ __launch_bounds__(256) void gemm_mfma(
    const unsigned short* __restrict__ A, int lda,
    const unsigned short* __restrict__ W, int ldw,
    void* __restrict__ C, int ldc, int Ksplit, size_t cSliceStride,
    const void* __restrict__ bias, size_t boff,
    void* __restrict__ C2, int ep, const int* __restrict__ flag,
    const unsigned short* __restrict__ Worig)
{
    __shared__ unsigned short As[128 * 64];
    __shared__ unsigned short Bs[128 * 64];
    int isbf = flag ? *flag : 1;
    const unsigned short* Wp = (Worig && isbf) ? Worig : W;
    int tid = threadIdx.x;
    int lane = tid & 63, w = tid >> 6;
    int m0 = blockIdx.x * 128, n0 = blockIdx.y * 128;
    int wm = (w >> 1) * 64, wn = (w & 1) * 64;
    int col = lane & 15, quad = lane >> 4;
    int kstart = blockIdx.z * Ksplit;

    f32x4 acc[4][4];
#pragma unroll
    for (int i = 0; i < 4; ++i)
#pragma unroll
        for (int j = 0; j < 4; ++j)
            acc[i][j] = (f32x4){0.f, 0.f, 0.f, 0.f};

    for (int kt = kstart; kt < kstart + Ksplit; kt += 64) {
#pragma unroll
        for (int i = 0; i < 4; ++i) {
            int seg = i * 4 + w;
            int q = seg * 64 + lane;           // 16B-chunk index 0..1023
            int r = q >> 3, cd = q & 7;
            int cs = cd ^ (r & 7);
            gld_lds16(A + (size_t)(m0 + r) * lda + kt + cs * 8, &As[seg * 512]);
            gld_lds16(Wp + (size_t)(n0 + r) * ldw + kt + cs * 8, &Bs[seg * 512]);
        }
        __syncthreads();
#pragma unroll
        for (int ks = 0; ks < 2; ++ks) {
            bf16x8 af[4], bfr[4];
#pragma unroll
            for (int t = 0; t < 4; ++t) {
                int rowA = wm + t * 16 + col;
                int ca = ks * 4 + quad;
                af[t]  = *(const bf16x8*)&As[rowA * 64 + ((ca ^ (rowA & 7)) * 8)];
                int rowB = wn + t * 16 + col;
                bfr[t] = *(const bf16x8*)&Bs[rowB * 64 + ((ca ^ (rowB & 7)) * 8)];
            }
#pragma unroll
            for (int tm = 0; tm < 4; ++tm)
#pragma unroll
                for (int tn = 0; tn < 4; ++tn)
                    acc[tm][tn] = __builtin_amdgcn_mfma_f32_16x16x32_bf16(
                        af[tm], bfr[tn], acc[tm][tn], 0, 0, 0);
        }
        __syncthreads();
    }

    float* Cp = (float*)C + (size_t)blockIdx.z * cSliceStride;
#pragma unroll
    for (int tm = 0; tm < 4; ++tm)
#pragma unroll
        for (int tn = 0; tn < 4; ++tn)
#pragma unroll
            for (int rg = 0; rg < 4; ++rg) {
                int gm = m0 + wm + tm * 16 + quad * 4 + rg;
                int gn = n0 + wn + tn * 16 + col;
                float v = acc[tm][tn][rg];
                if (ep == 0) {
                    Cp[(size_t)gm * ldc + gn] = v;
                } else { // ep == 2: softplus(v+bias) -> bf16
                    v = softplusf_(v + ldin(bias, boff + gn, isbf));
                    ((unsigned short*)C)[(size_t)gm * ldc + gn] = f2bf(v);
                }
            }
}

// ---- x_proj direct GEMM: 32x128 tile, K=DI (no split-K, no reduce) ----
// xdbl[M,96] fp32 + dt16[M,64] bf16 written in-epilogue. 128 blocks, 4 waves;
// wave w owns cols w*32..w*32+31. Same XOR-chunk LDS scheme as gemm_mfma.
__global__ __launch_bounds__(256) void gemm_xproj(
    const unsigned short* __restrict__ A,   // xc16 [M, DI]
    const unsigned short* __restrict__ W,   // wbuf XW [128, DI]
    float* __restrict__ xdbl,               // [M, 96]
    unsigned short* __restrict__ dt16)      // [M, 64]
{
    __shared__ unsigned short As[32 * 64];
    __shared__ unsigned short Bs[128 * 64];
    int tid = threadIdx.x;
    int lane = tid & 63, w = tid >> 6;
    int m0 = blockIdx.x * 32;
    int col = lane & 15, quad = lane >> 4;

    f32x4 acc[2][2];
#pragma unroll
    for (int i = 0; i < 2; ++i)
#pragma unroll
        for (int j = 0; j < 2; ++j)
            acc[i][j] = (f32x4){0.f, 0.f, 0.f, 0.f};

    for (int kt = 0; kt < DI_; kt += 64) {
        {   // A: 256 chunks, one per thread (rows 0..31)
            int r = tid >> 3, cd = tid & 7, cs = cd ^ (r & 7);
            gld_lds16(A + (size_t)(m0 + r) * DI_ + kt + cs * 8, &As[w * 512]);
        }
#pragma unroll
        for (int i = 0; i < 4; ++i) {        // B: 16 segments (rows 0..127)
            int seg = i * 4 + w;
            int q = seg * 64 + lane;
            int r = q >> 3, cd = q & 7, cs = cd ^ (r & 7);
            gld_lds16(W + (size_t)r * DI_ + kt + cs * 8, &Bs[seg * 512]);
        }
        __syncthreads();
#pragma unroll
        for (int ks = 0; ks < 2; ++ks) {
            int ca = ks * 4 + quad;
            bf16x8 af[2], bfr[2];
#pragma unroll
            for (int t = 0; t < 2; ++t) {
                int rowA = t * 16 + col;
                af[t] = *(const bf16x8*)&As[rowA * 64 + ((ca ^ (rowA & 7)) * 8)];
                int rowB = w * 32 + t * 16 + col;
                bfr[t] = *(const bf16x8*)&Bs[rowB * 64 + ((ca ^ (rowB & 7)) * 8)];
            }
#pragma unroll
            for (int tm = 0; tm < 2; ++tm)
#pragma unroll
                for (int tn = 0; tn < 2; ++tn)
                    acc[tm][tn] = __builtin_amdgcn_mfma_f32_16x16x32_bf16(
                        af[tm], bfr[tn], acc[tm][tn], 0, 0, 0);
        }
        __syncthreads();
    }
#pragma unroll
    for (int tm = 0; tm < 2; ++tm)
#pragma unroll
        for (int tn = 0; tn < 2; ++tn)
#pragma unroll
            for (int rg = 0; rg < 4; ++rg) {
                int gm = m0 + tm * 16 + quad * 4 + rg;
                int gn = w * 32 + tn * 16 + col;
                float v = acc[tm][tn][rg];
                if (gn < NXD_) xdbl[(size_t)gm * NXD_ + gn] = v;
                if (gn < DTR_) dt16[(size_t)gm * DTR_ + gn] = f2bf(v);
            }
}

// ---- 8-phase 256x256 in_proj GEMM (m201 structure, plain HIP) ----
template <int KS, int MH, int RB, int CHK>
__device__ __forceinline__ void g8_phase(
    unsigned baseA, unsigned baseB,
    bf16x8 (&af)[4], bf16x8 (&bfr)[4], f32x4 (&acc)[8][4],
    int doStage, int st_t, int st_isB, int st_ks,
    const unsigned short* srcA, const unsigned short* srcW,
    unsigned short* ldsb, int w)
{
    if (RB) {
#pragma unroll
        for (int j = 0; j < 4; ++j)
            bfr[j] = ds_read128_(baseB + j * 2048 + KS * 1024);
    }
#pragma unroll
    for (int f = 0; f < 4; ++f)
        af[f] = ds_read128_(baseA + MH * 8192 + f * 2048 + KS * 1024);
    if (doStage) {
        const unsigned short* s0 = (st_isB ? srcW : srcA)
            + (size_t)w * 16 * E_ + st_t * 64 + st_ks * 32;
        unsigned short* d0 = ldsb + (st_t & 1) * 32768 + st_isB * 16384
            + w * 1024 + st_ks * 512;
        gld_lds16(s0, d0);
        gld_lds16(s0 + (size_t)8 * 16 * E_, d0 + 8 * 1024);
    }
    __builtin_amdgcn_s_barrier();
    asm volatile("s_waitcnt lgkmcnt(0)" ::: "memory");
    __builtin_amdgcn_sched_barrier(0);
    __builtin_amdgcn_s_setprio(1);
#pragma unroll
    for (int f = 0; f < 4; ++f)
#pragma unroll
        for (int j = 0; j < 4; ++j)
            acc[MH * 4 + f][j] = __builtin_amdgcn_mfma_f32_16x16x32_bf16(
                af[f], bfr[j], acc[MH * 4 + f][j], 0, 0, 0);
    __builtin_amdgcn_s_setprio(0);
    if (CHK == 8) { asm volatile("s_waitcnt vmcnt(8)" ::: "memory"); __builtin_amdgcn_sched_barrier(0); }
    if (CHK == 4) { asm volatile("s_waitcnt vmcnt(4)" ::: "memory"); __builtin_amdgcn_sched_barrier(0); }
    if (CHK == 0) { asm volatile("s_waitcnt vmcnt(0)"  ::: "memory"); __builtin_amdgcn_sched_barrier(0); }
    __builtin_amdgcn_s_barrier();
}

__global__ __launch_bounds__(512) void gemm_inproj8(
    const unsigned short* __restrict__ A,      // [M_, E_] bf16
    const unsigned short* __restrict__ Wbuf,   // converted weights
    const unsigned short* __restrict__ Worig,  // original (bf16 path)
    const int* __restrict__ flag,
    unsigned short* __restrict__ Cx,           // [M_, DI_] bf16
    unsigned short* __restrict__ Cz)           // [M_, DI_] bf16
{
    __shared__ unsigned short lds[65536];      // 2 bufs * (A 16K + B 16K shorts)
    const unsigned short* W = (*flag) ? Worig : Wbuf;
    int tid = threadIdx.x;
    int lane = tid & 63, w = tid >> 6;         // 8 waves
    int wr = w >> 2, wc = w & 3;               // 2(M) x 4(N)
    int col = lane & 15, quad = lane >> 4;

    int flat = blockIdx.y * 16 + blockIdx.x;
    int nn = (flat & 7) * 32 + (flat >> 3);
    int cch = nn >> 5, wi = nn & 31;
    int bx = (cch & 3) * 4 + (wi & 3);
    int by = (cch >> 2) * 8 + (wi >> 2);
    int m0 = bx * 256, n0 = by * 256;

    const unsigned short* srcA = A + (size_t)(m0 + (lane & 15)) * E_ + (lane >> 4) * 8;
    const unsigned short* srcW = W + (size_t)(n0 + (lane & 15)) * E_ + (lane >> 4) * 8;

    unsigned baseA0 = (unsigned)(wr * 8 * 2048 + quad * 256 + col * 16);
    unsigned baseB0 = (unsigned)(32768 + wc * 4 * 2048 + quad * 256 + col * 16);
    unsigned baseA1 = baseA0 + 65536, baseB1 = baseB0 + 65536;

    f32x4 acc[8][4];
#pragma unroll
    for (int i = 0; i < 8; ++i)
#pragma unroll
        for (int j = 0; j < 4; ++j)
            acc[i][j] = (f32x4){0.f, 0.f, 0.f, 0.f};
    bf16x8 af[4], bfr[4];

#define G8STAGE(t_, isB_, ks_) { \
    const unsigned short* s0 = ((isB_) ? srcW : srcA) + (size_t)w * 16 * E_ + (t_) * 64 + (ks_) * 32; \
    unsigned short* d0 = lds + ((t_) & 1) * 32768 + (isB_) * 16384 + w * 1024 + (ks_) * 512; \
    gld_lds16(s0, d0); gld_lds16(s0 + (size_t)8 * 16 * E_, d0 + 8 * 1024); }

    G8STAGE(0, 0, 0) G8STAGE(0, 1, 0) G8STAGE(0, 0, 1) G8STAGE(0, 1, 1)
    G8STAGE(1, 0, 0) G8STAGE(1, 1, 0)
    asm volatile("s_waitcnt vmcnt(8)" ::: "memory");
    __builtin_amdgcn_sched_barrier(0);
    __builtin_amdgcn_s_barrier();

    for (int i = 0; i < 7; ++i) {              // K=1024 -> 16 tiles -> 8 pairs
        int t1 = 2 * i + 1, t2 = 2 * i + 2, t3 = 2 * i + 3;
        g8_phase<0,0,1,-1>(baseA0, baseB0, af, bfr, acc, 1, t1, 0, 1, srcA, srcW, lds, w);
        g8_phase<0,1,0, 8>(baseA0, baseB0, af, bfr, acc, 1, t1, 1, 1, srcA, srcW, lds, w);
        g8_phase<1,0,1,-1>(baseA0, baseB0, af, bfr, acc, 1, t2, 0, 0, srcA, srcW, lds, w);
        g8_phase<1,1,0, 8>(baseA0, baseB0, af, bfr, acc, 1, t2, 1, 0, srcA, srcW, lds, w);
        g8_phase<0,0,1,-1>(baseA1, baseB1, af, bfr, acc, 1, t2, 0, 1, srcA, srcW, lds, w);
        g8_phase<0,1,0, 8>(baseA1, baseB1, af, bfr, acc, 1, t2, 1, 1, srcA, srcW, lds, w);
        g8_phase<1,0,1,-1>(baseA1, baseB1, af, bfr, acc, 1, t3, 0, 0, srcA, srcW, lds, w);
        g8_phase<1,1,0, 8>(baseA1, baseB1, af, bfr, acc, 1, t3, 1, 0, srcA, srcW, lds, w);
    }
    g8_phase<0,0,1,-1>(baseA0, baseB0, af, bfr, acc, 1, 15, 0, 1, srcA, srcW, lds, w);
    g8_phase<0,1,0, 8>(baseA0, baseB0, af, bfr, acc, 1, 15, 1, 1, srcA, srcW, lds, w);
    g8_phase<1,0,1,-1>(baseA0, baseB0, af, bfr, acc, 0, 0, 0, 0, srcA, srcW, lds, w);
    g8_phase<1,1,0, 4>(baseA0, baseB0, af, bfr, acc, 0, 0, 0, 0, srcA, srcW, lds, w);
    g8_phase<0,0,1,-1>(baseA1, baseB1, af, bfr, acc, 0, 0, 0, 0, srcA, srcW, lds, w);
    g8_phase<0,1,0, 0>(baseA1, baseB1, af, bfr, acc, 0, 0, 0, 0, srcA, srcW, lds, w);
    g8_phase<1,0,1,-1>(baseA1, baseB1, af, bfr, acc, 0, 0, 0, 0, srcA, srcW, lds, w);
    g8_phase<1,1,0,-1>(baseA1, baseB1, af, bfr, acc, 0, 0, 0, 0, srcA, srcW, lds, w);

    unsigned short* dst = (n0 < DI_) ? Cx : Cz;
    int nb = (n0 < DI_) ? n0 : n0 - DI_;
#pragma unroll
    for (int tm = 0; tm < 8; ++tm)
#pragma unroll
        for (int tn = 0; tn < 4; ++tn)
#pragma unroll
            for (int rg = 0; rg < 4; ++rg) {
                int gm = m0 + wr * 128 + tm * 16 + quad * 4 + rg;
                int gn = nb + wc * 64 + tn * 16 + col;
                dst[(size_t)gm * DI_ + gn] = f2bf(acc[tm][tn][rg]);
            }
#undef G8STAGE
}

// transpose conv weights to fp32 [DC][DI] + bias fp32 [DI] (per layer)
__global__ __launch_bounds__(256) void conv_prep(
    const void* __restrict__ cw, size_t cwoff, const void* __restrict__ cb,
    size_t cboff, float* __restrict__ cwT, float* __restrict__ cbF,
    const int* __restrict__ flag)
{
    int isbf = *flag;
    int d = blockIdx.x * 256 + threadIdx.x;   // 0..DI_-1
#pragma unroll
    for (int k = 0; k < DC_; ++k)
        cwT[k * DI_ + d] = ldin(cw, cwoff + (size_t)d * DC_ + k, isbf);
    cbF[d] = ldin(cb, cboff + d, isbf);
}

// causal depthwise conv + bias + SiLU, vectorized: 8 channels x 4 timesteps
#define CT_ 4
__global__ __launch_bounds__(256) void conv_silu_v(
    const unsigned short* __restrict__ xcr16, const float* __restrict__ cwT,
    const float* __restrict__ cbF, unsigned short* __restrict__ xc16)
{
    int g = blockIdx.x;                       // row group: rows g*4..g*4+3
    int bl0 = g * CT_;
    int l0 = bl0 & (L_ - 1);                  // within-batch (L divisible by 4)
    int d = threadIdx.x * 8;                  // 8 channels

    float w[DC_][8], bias[8];
#pragma unroll
    for (int k = 0; k < DC_; ++k) {
        *(float4*)&w[k][0] = *(const float4*)&cwT[k * DI_ + d];
        *(float4*)&w[k][4] = *(const float4*)&cwT[k * DI_ + d + 4];
    }
    *(float4*)&bias[0] = *(const float4*)&cbF[d];
    *(float4*)&bias[4] = *(const float4*)&cbF[d + 4];

    float xr[DC_ - 1 + CT_][8];               // rows l0-3 .. l0+3
#pragma unroll
    for (int r = 0; r < DC_ - 1 + CT_; ++r) {
        int l = l0 - (DC_ - 1) + r;
        if (l >= 0) {
            bf16x8 v = *(const bf16x8*)&xcr16[(size_t)(bl0 - (DC_ - 1) + r) * DI_ + d];
#pragma unroll
            for (int j = 0; j < 8; ++j) xr[r][j] = bf2f((unsigned short)v[j]);
        } else {
#pragma unroll
            for (int j = 0; j < 8; ++j) xr[r][j] = 0.f;
        }
    }

#pragma unroll
    for (int t = 0; t < CT_; ++t) {
        float acc[8];
#pragma unroll
        for (int j = 0; j < 8; ++j) acc[j] = bias[j];
#pragma unroll
        for (int k = 0; k < DC_; ++k)
#pragma unroll
            for (int j = 0; j < 8; ++j)
                acc[j] = fmaf(w[k][j], xr[t + k][j], acc[j]);
        bf16x8 ov;
#pragma unroll
        for (int j = 0; j < 8; ++j) {
            float s = acc[j] * sigmoidf_(acc[j]);
            ov[j] = (short)f2bf(s);
        }
        *(bf16x8*)&xc16[(size_t)(bl0 + t) * DI_ + d] = ov;
    }
}

// pass1: chunk-local end state (zero init) + sum(delta); delta bf16
__global__ __launch_bounds__(256) void scan_part1(
    const unsigned short* __restrict__ dl16, const unsigned short* __restrict__ xc16,
    const float* __restrict__ xdbl,
    const void* __restrict__ A_log, size_t aoff,
    float* __restrict__ sumdbuf, float* __restrict__ scrS,
    const int* __restrict__ flags, int layer)
{
    int isbf = flags[0], fast = flags[1 + layer];
    __shared__ float bs[LC_][16];
    int c = blockIdx.y;
    int b = blockIdx.x >> 3;
    int d = ((blockIdx.x & 7) << 8) + threadIdx.x;
    for (int i = threadIdx.x; i < LC_ * 16; i += 256) {
        int l = i >> 4, n = i & 15;
        bs[l][n] = xdbl[((size_t)b * L_ + c * LC_ + l) * NXD_ + DTR_ + n];
    }
    __syncthreads();
    float a2[16];
#pragma unroll
    for (int n = 0; n < 16; ++n)
        a2[n] = -expf_(ldin(A_log, aoff + (size_t)d * DS_ + n, isbf)) * LOG2E_;
    float s[16] = {};
    float sumd = 0.f;
    const unsigned short* dp = dl16 + ((size_t)b * L_ + c * LC_) * DI_ + d;
    const unsigned short* up = xc16 + ((size_t)b * L_ + c * LC_) * DI_ + d;
    for (int l = 0; l < LC_; ++l) {
        float dv = bf2f(dp[(size_t)l * DI_]);
        float u  = bf2f(up[(size_t)l * DI_]);
        sumd += dv;
        float dvu = dv * u;
        float e[16];
        expvec(fast, dv, a2, e);
        float4 b0 = *(const float4*)&bs[l][0];
        float4 b1 = *(const float4*)&bs[l][4];
        float4 b2 = *(const float4*)&bs[l][8];
        float4 b3 = *(const float4*)&bs[l][12];
        float bv[16] = {b0.x,b0.y,b0.z,b0.w, b1.x,b1.y,b1.z,b1.w,
                        b2.x,b2.y,b2.z,b2.w, b3.x,b3.y,b3.z,b3.w};
#pragma unroll
        for (int n = 0; n < 16; ++n)
            s[n] = fmaf(e[n], s[n], dvu * bv[n]);
    }
    int g = b * DI_ + d;
    sumdbuf[(size_t)c * (B_ * DI_) + g] = sumd;
    size_t base = ((size_t)c * (B_ * DI_) + g) * 16;
#pragma unroll
    for (int q = 0; q < 4; ++q)
        *(float4*)&scrS[base + q * 4] =
            make_float4(s[q*4], s[q*4+1], s[q*4+2], s[q*4+3]);
}

// sequential combine: scrS[c] becomes the state ENTERING chunk c.
__global__ __launch_bounds__(256) void scan_combine(
    const float* __restrict__ sumdbuf, float* __restrict__ scrS,
    const void* __restrict__ A_log, size_t aoff, const int* __restrict__ flags)
{
    int isbf = flags[0];
    int t = blockIdx.x * 256 + threadIdx.x;    // g*16+n
    int g = t >> 4, n = t & 15;
    int d = g & (DI_ - 1);
    float a2 = -expf_(ldin(A_log, aoff + (size_t)d * DS_ + n, isbf)) * LOG2E_;
    float sd[NCH_], sl[NCH_];
#pragma unroll
    for (int c = 0; c < NCH_; ++c) {
        sd[c] = sumdbuf[(size_t)c * (B_ * DI_) + g];
        sl[c] = scrS[(size_t)c * (B_ * DI_ * 16) + t];
    }
    float s = 0.f;
#pragma unroll
    for (int c = 0; c < NCH_; ++c) {
        float P = __builtin_amdgcn_exp2f(a2 * sd[c]);
        float nxt = fmaf(P, s, sl[c]);
        scrS[(size_t)c * (B_ * DI_ * 16) + t] = s;
        s = nxt;
    }
}

// pass2: re-run chunk with correct init; y (bf16) written in place into xc16
__global__ __launch_bounds__(256) void scan_part2(
    const unsigned short* __restrict__ dl16, unsigned short* __restrict__ xc16,
    const float* __restrict__ xdbl, const unsigned short* __restrict__ z,
    const void* __restrict__ A_log, size_t aoff,
    const void* __restrict__ Dskip, size_t doff,
    const float* __restrict__ scrS, const int* __restrict__ flags, int layer)
{
    int isbf = flags[0], fast = flags[1 + layer];
    __shared__ float bs[LC_][32];              // [l][n]=B, [l][16+n]=C
    int c = blockIdx.y;
    int b = blockIdx.x >> 3;
    int d = ((blockIdx.x & 7) << 8) + threadIdx.x;
    for (int i = threadIdx.x; i < LC_ * 32; i += 256) {
        int l = i >> 5, n = i & 31;
        bs[l][n] = xdbl[((size_t)b * L_ + c * LC_ + l) * NXD_ + DTR_ + n];
    }
    __syncthreads();
    float a2[16];
#pragma unroll
    for (int n = 0; n < 16; ++n)
        a2[n] = -expf_(ldin(A_log, aoff + (size_t)d * DS_ + n, isbf)) * LOG2E_;
    float Dv = ldin(Dskip, doff + d, isbf);
    int g = b * DI_ + d;
    size_t sbase = ((size_t)c * (B_ * DI_) + g) * 16;
    float s[16];
#pragma unroll
    for (int q = 0; q < 4; ++q) {
        float4 sv = *(const float4*)&scrS[sbase + q * 4];
        s[q*4] = sv.x; s[q*4+1] = sv.y; s[q*4+2] = sv.z; s[q*4+3] = sv.w;
    }

    const unsigned short* dp = dl16 + ((size_t)b * L_ + c * LC_) * DI_ + d;
    unsigned short* up = xc16 + ((size_t)b * L_ + c * LC_) * DI_ + d;
    const unsigned short* zp = z + ((size_t)b * L_ + c * LC_) * DI_ + d;
    for (int l = 0; l < LC_; ++l) {
        float dv = bf2f(dp[(size_t)l * DI_]);
        float u  = bf2f(up[(size_t)l * DI_]);
        float dvu = dv * u;
        float e[16];
        expvec(fast, dv, a2, e);
        float4 b0 = *(const float4*)&bs[l][0];
        float4 b1 = *(const float4*)&bs[l][4];
        float4 b2 = *(const float4*)&bs[l][8];
        float4 b3 = *(const float4*)&bs[l][12];
        float4 c0 = *(const float4*)&bs[l][16];
        float4 c1 = *(const float4*)&bs[l][20];
        float4 c2 = *(const float4*)&bs[l][24];
        float4 c3 = *(const float4*)&bs[l][28];
        float bv[16] = {b0.x,b0.y,b0.z,b0.w, b1.x,b1.y,b1.z,b1.w,
                        b2.x,b2.y,b2.z,b2.w, b3.x,b3.y,b3.z,b3.w};
        float cv[16] = {c0.x,c0.y,c0.z,c0.w, c1.x,c1.y,c1.z,c1.w,
                        c2.x,c2.y,c2.z,c2.w, c3.x,c3.y,c3.z,c3.w};
        float y = 0.f;
#pragma unroll
        for (int n = 0; n < 16; ++n) {
            s[n] = fmaf(e[n], s[n], dvu * bv[n]);
            y = fmaf(s[n], cv[n], y);
        }
        float zv = bf2f(zp[(size_t)l * DI_]);
        up[(size_t)l * DI_] = f2bf((y + u * Dv) * (zv * sigmoidf_(zv)));
    }
}

// h = rmsnorm(y + h) * norm_w ; also bf16 copy; optionally final out
__global__ __launch_bounds__(256) void rmsnorm_kernel(
    const float* __restrict__ y0,
    float* __restrict__ h, unsigned short* __restrict__ h16,
    const void* __restrict__ nw, size_t nwoff, void* __restrict__ out,
    int write_out, const int* __restrict__ flag)
{
    int isbf = *flag;
    __shared__ float red[4];
    int row = blockIdx.x;
    float* hp = h + (size_t)row * E_;
    float v[4]; float ss = 0.f;
#pragma unroll
    for (int i = 0; i < 4; ++i) {
        int e = threadIdx.x + i * 256;
        size_t idx = (size_t)row * E_ + e;
        v[i] = y0[idx] + hp[e];
        ss += v[i] * v[i];
    }
#pragma unroll
    for (int off = 1; off < 64; off <<= 1) ss += __shfl_xor(ss, off, 64);
    if ((threadIdx.x & 63) == 0) red[threadIdx.x >> 6] = ss;
    __syncthreads();
    ss = red[0] + red[1] + red[2] + red[3];
    float scale = rsqrtf(ss * (1.f / E_) + 1e-6f);
#pragma unroll
    for (int i = 0; i < 4; ++i) {
        int e = threadIdx.x + i * 256;
        float hv = v[i] * scale * ldin(nw, nwoff + e, isbf);
        hp[e] = hv;
        h16[(size_t)row * E_ + e] = f2bf(hv);
        if (write_out) {
            size_t oi = (size_t)row * E_ + e;
            if (isbf) ((unsigned short*)out)[oi] = f2bf(hv);
            else      ((float*)out)[oi] = hv;
        }
    }
}

extern "C" void kernel_launch(void* const* d_in, const int* in_sizes, int n_in,
                              void* d_out, int out_size, void* d_ws, size_t ws_size,
                              hipStream_t stream)
{
    const void* x    = d_in[0];
    const void* pos  = d_in[1];
    const void* inw  = d_in[2];
    const void* cw   = d_in[3];
    const void* cb   = d_in[4];
    const void* xw   = d_in[5];
    const void* dtw  = d_in[6];
    const void* dtb  = d_in[7];
    const void* alog = d_in[8];
    const void* dsk  = d_in[9];
    const void* ow   = d_in[10];
    const void* nw   = d_in[11];

    float* ws = (float*)d_ws;
    float* h      = ws;                                        // 4,194,304 f
    unsigned short* h16  = (unsigned short*)(ws + 4194304);    // 2,097,152 f
    unsigned short* z16  = (unsigned short*)(ws + 6291456);    // 4,194,304 f
    unsigned short* xc16 = (unsigned short*)(ws + 10485760);   // 4,194,304 f
    float* D      = ws + 14680064;                             // 8,388,608 f (delta16 -> yout)
    float* R      = ws + 23068672;                             // 4,194,304 f (xcr16/scrS)
    float* xdbl   = ws + 27262976;                             //   393,216 f
    unsigned short* dt16 = (unsigned short*)(ws + 27656192);   //   131,072 f
    float* sumd   = ws + 27787264;                             //   262,144 f
    unsigned short* wbuf = (unsigned short*)(ws + 28049408);   // 3,342,336 f
    int* flags    = (int*)(ws + 31391744);
    // total ~125.6 MB (same proven footprint)

    unsigned short* xcr16 = (unsigned short*)R;    // in_proj xc_raw (bf16)
    float* scrS    = R;                            // scan chunk states (8.4 MB)
    unsigned short* dl16 = (unsigned short*)D;     // delta bf16 (dead before yout)
    float* yout0 = D;
    // conv weight transpose lives in sumd (dead until scan_part1)
    float* cwT = sumd;                             // DC_*DI_ = 8192 f
    float* cbF = sumd + DC_ * DI_;                 // DI_ = 2048 f

    detect_kernel<<<1, 256, 0, stream>>>((const unsigned*)x, flags);
    chk_alog<<<NL_ * DI_ * DS_ / 256, 256, 0, stream>>>(alog, flags);
    add_pos_kernel<<<M_ * E_ / 256, 256, 0, stream>>>(x, pos, h, h16, flags);

    for (int layer = 0; layer < NL_; ++layer) {
        const unsigned short* inws = (const unsigned short*)inw + (size_t)layer * 2 * DI_ * E_;
        const unsigned short* dtws = (const unsigned short*)dtw + (size_t)layer * DI_ * DTR_;
        const unsigned short* ows  = (const unsigned short*)ow  + (size_t)layer * E_ * DI_;

        cvt_layer_kernel<<<WB_TOT_ / 256, 256, 0, stream>>>(
            inw, xw, dtw, ow, layer, wbuf, flags);
        conv_prep<<<DI_ / 256, 256, 0, stream>>>(
            cw, (size_t)layer * DI_ * DC_, cb, (size_t)layer * DI_, cwT, cbF, flags);

        // fused in_proj: [xc_raw | z] = h @ in_proj^T  (256x256 8-phase)
        gemm_inproj8<<<dim3(M_ / 256, 2 * DI_ / 256, 1), 512, 0, stream>>>(
            h16, wbuf + WB_IN_, inws, flags, xcr16, z16);
        // xc = silu(conv(xc_raw)+cb), vectorized 8ch x 4t per thread
        conv_silu_v<<<M_ / CT_, 256, 0, stream>>>(xcr16, cwT, cbF, xc16);
        // x_dbl direct: xdbl fp32 [M,96] + dt16 bf16 [M,64], no split-K
        gemm_xproj<<<M_ / 32, 256, 0, stream>>>(
            xc16, wbuf + WB_XW_, xdbl, dt16);
        // delta = softplus(dt @ dt_proj^T + dtb) -> dl16 (bf16)
        gemm_mfma<<<dim3(M_ / 128, DI_ / 128, 1), 256, 0, stream>>>(
            dt16, DTR_, wbuf + WB_DTW_, DTR_, dl16, DI_, DTR_, 0,
            dtb, (size_t)layer * DI_, nullptr, 2, flags, dtws);
        // chunked scan; y bf16 in place into xc16
        scan_part1<<<dim3(B_ * DI_ / 256, NCH_), 256, 0, stream>>>(
            dl16, xc16, xdbl, alog, (size_t)layer * DI_ * DS_, sumd, scrS, flags, layer);
        scan_combine<<<B_ * DI_ * DS_ / 256, 256, 0, stream>>>(
            sumd, scrS, alog, (size_t)layer * DI_ * DS_, flags);
        scan_part2<<<dim3(B_ * DI_ / 256, NCH_), 256, 0, stream>>>(
            dl16, xc16, xdbl, z16, alog, (size_t)layer * DI_ * DS_,
            dsk, (size_t)layer * DI_, scrS, flags, layer);
        // yout = y @ out_proj^T, single pass (grid 32x8 = 256 blocks)
        gemm_mfma<<<dim3(M_ / 128, E_ / 128, 1), 256, 0, stream>>>(
            xc16, DI_, wbuf + WB_OW_, DI_, yout0, E_, DI_, 0,
            nullptr, 0, nullptr, 0, flags, ows);
        // h = rmsnorm(yout + h); emit output on last layer
        rmsnorm_kernel<<<M_, 256, 0, stream>>>(
            yout0, h, h16, nw, (size_t)layer * E_, d_out,
            layer == NL_ - 1 ? 1 : 0, flags);
    }
}

// Round 6
// 583.331 us; speedup vs baseline: 1.1084x; 1.1084x over previous
//
#include <hip/hip_runtime.h>

// MambaTower: B=2, L=2048, E=1024, NL=2, DI=2048, DS=16, DC=4, DTR=64
#define B_   2
#define L_   2048
#define E_   1024
#define NL_  2
#define DI_  2048
#define DS_  16
#define DC_  4
#define DTR_ 64
#define NXD_ 96            // DTR + 2*DS
#define M_   (B_ * L_)     // 4096 rows
#define NCH_ 64            // scan chunks
#define LC_  32            // timesteps per chunk

typedef __attribute__((ext_vector_type(8))) short bf16x8;
typedef __attribute__((ext_vector_type(4))) float f32x4;

__device__ __forceinline__ float bf2f(unsigned short u) {
    return __uint_as_float(((unsigned)u) << 16);
}
__device__ __forceinline__ unsigned short f2bf(float f) {
    unsigned u = __float_as_uint(f);
    u += 0x7fff + ((u >> 16) & 1);
    return (unsigned short)(u >> 16);
}

#define LOG2E_ 1.44269504f
#define LN2_   0.69314718f

// hardware-transcendental forms: v_exp_f32 computes 2^x, v_log_f32 computes log2(x)
__device__ __forceinline__ float sigmoidf_(float x) {
    return __builtin_amdgcn_rcpf(1.f + __builtin_amdgcn_exp2f(-x * LOG2E_));
}
__device__ __forceinline__ float softplusf_(float x) {
    float e = __builtin_amdgcn_exp2f(x * LOG2E_);
    float s = LN2_ * __builtin_amdgcn_logf(1.f + e);
    return x > 15.f ? x : s;
}
__device__ __forceinline__ float expf_(float x) {       // e^x
    return __builtin_amdgcn_exp2f(x * LOG2E_);
}
__device__ __forceinline__ float ldin(const void* p, size_t i, int isbf) {
    return isbf ? bf2f(((const unsigned short*)p)[i]) : ((const float*)p)[i];
}
__device__ __forceinline__ void gld_lds16(const unsigned short* g, unsigned short* l) {
    __builtin_amdgcn_global_load_lds(
        (const __attribute__((address_space(1))) unsigned int*)g,
        (__attribute__((address_space(3))) unsigned int*)l, 16, 0, 0);
}
// opaque LDS read (compiler can't alias with global_load_lds; paired with
// explicit lgkmcnt(0)+sched_barrier before use)
__device__ __forceinline__ bf16x8 ds_read128_(unsigned byteoff) {
    bf16x8 r;
    asm volatile("ds_read_b128 %0, %1" : "=&v"(r) : "v"(byteoff));
    return r;
}

// e8[j] = exp(dv*a[sub*8+j]) for 8 states; fast path uses a[n]=(n+1)*a0
// (validated by chk_alog): q = exp2(dv*a0*log2e); e = q^(n+1).
// Same product factorizations as the original 16-wide expvec -> bit-identical.
__device__ __forceinline__ void expvec8(int fast, int sub, float dv, float a2r0,
                                        const float* a2, float* e) {
    if (fast) {
        float q1 = __builtin_amdgcn_exp2f(dv * a2r0);
        float q2 = q1 * q1, q4 = q2 * q2, q8 = q4 * q4;
        e[0] = q1;      e[1] = q2;      e[2] = q2 * q1; e[3] = q4;
        e[4] = q4 * q1; e[5] = q4 * q2; e[6] = e[5] * q1; e[7] = q8;
        float m = sub ? q8 : 1.f;
#pragma unroll
        for (int j = 0; j < 8; ++j) e[j] *= m;
    } else {
#pragma unroll
        for (int j = 0; j < 8; ++j) e[j] = __builtin_amdgcn_exp2f(dv * a2[j]);
    }
}

// flags[0]=dtype(1=bf16), flags[1+layer]=A_log linear-structure fast flag
__global__ __launch_bounds__(256) void detect_kernel(const unsigned* __restrict__ x,
                                                     int* __restrict__ flags)
{
    __shared__ int cnt;
    if (threadIdx.x == 0) cnt = 0;
    __syncthreads();
    unsigned v = x[threadIdx.x];
    int e = (v >> 7) & 0xFF;
    if (e >= 90 && e <= 140) atomicAdd(&cnt, 1);
    __syncthreads();
    if (threadIdx.x == 0) {
        flags[0] = (cnt >= 192) ? 1 : 0;
        flags[1] = 1;
        flags[2] = 1;
    }
}

// validate a[n] ~= (n+1)*a[0] for every (layer,d); clear fast flag on fail
__global__ __launch_bounds__(256) void chk_alog(
    const void* __restrict__ alog, int* __restrict__ flags)
{
    int isbf = flags[0];
    int i = blockIdx.x * 256 + threadIdx.x;      // NL*DI*DS
    int layer = i / (DI_ * DS_);
    int n = i & (DS_ - 1);
    float a  = -expf_(ldin(alog, i, isbf));
    float a0 = -expf_(ldin(alog, i - n, isbf));
    float want = (n + 1) * a0;
    if (fabsf(a - want) > 0.02f * fabsf(want))
        atomicAnd(&flags[1 + layer], 0);
}

// convert weights to bf16 into wbuf (xw padded 96->128 rows). When input is
// already bf16 the in/dt/ow copies are identity -> consumers read the input
// tensors directly and we only build the padded xw block here.
#define WB_IN_  0
#define WB_XW_  4194304
#define WB_DTW_ 4456448
#define WB_OW_  4587520
#define WB_TOT_ 6684672
__global__ __launch_bounds__(256) void cvt_layer_kernel(
    const void* __restrict__ inw, const void* __restrict__ xw,
    const void* __restrict__ dtw, const void* __restrict__ ow,
    int layer, unsigned short* __restrict__ wbuf, const int* __restrict__ flag)
{
    int isbf = *flag;
    int i = blockIdx.x * 256 + threadIdx.x;    // 0..WB_TOT_-1
    if (isbf && (i < WB_XW_ || i >= WB_DTW_)) return;   // identity regions skipped
    unsigned short v;
    if (i < WB_XW_) {
        v = isbf ? ((const unsigned short*)inw)[(size_t)layer * 2 * DI_ * E_ + i]
                 : f2bf(((const float*)inw)[(size_t)layer * 2 * DI_ * E_ + i]);
    } else if (i < WB_DTW_) {
        int j = i - WB_XW_; int r = j >> 11, k = j & (DI_ - 1);
        v = (r < NXD_)
          ? (isbf ? ((const unsigned short*)xw)[(size_t)layer * NXD_ * DI_ + (size_t)r * DI_ + k]
                  : f2bf(((const float*)xw)[(size_t)layer * NXD_ * DI_ + (size_t)r * DI_ + k]))
          : (unsigned short)0;
    } else if (i < WB_OW_) {
        int j = i - WB_DTW_;
        v = isbf ? ((const unsigned short*)dtw)[(size_t)layer * DI_ * DTR_ + j]
                 : f2bf(((const float*)dtw)[(size_t)layer * DI_ * DTR_ + j]);
    } else {
        int j = i - WB_OW_;
        v = isbf ? ((const unsigned short*)ow)[(size_t)layer * E_ * DI_ + j]
                 : f2bf(((const float*)ow)[(size_t)layer * E_ * DI_ + j]);
    }
    wbuf[i] = v;
}

// h = x + pos (fp32 + bf16 copies)
__global__ __launch_bounds__(256) void add_pos_kernel(
    const void* __restrict__ x, const void* __restrict__ pos,
    float* __restrict__ h, unsigned short* __restrict__ h16,
    const int* __restrict__ flag)
{
    int isbf = *flag;
    int i = blockIdx.x * 256 + threadIdx.x;
    float v = ldin(x, i, isbf) + ldin(pos, i & (L_ * E_ - 1), isbf);
    h[i] = v;
    h16[i] = f2bf(v);
}

// ---- MFMA GEMM: C[M,N] = A[M,K](bf16) * W[N,K](bf16)^T ----
// 128x128 tile, BK=64, 256 threads = 4 waves (2x2 of 64x64).
// XOR-swizzled LDS chunk layout (0 bank conflicts, coalesced staging).
// blockIdx.z = split-K slice; ep0 partials advance C by z*cSliceStride.
// ep: 0=fp32 store, 2=softplus(v+bias[n]) -> bf16 store
// Worig: when non-null and *flag (bf16 inputs), use original weight tensor.
__global__ __launch_bounds__(256) void gemm_mfma(
    const unsigned short* __restrict__ A, int lda,
    const unsigned short* __restrict__ W, int ldw,
    void* __restrict__ C, int ldc, int Ksplit, size_t cSliceStride,
    const void* __restrict__ bias, size_t boff,
    void* __restrict__ C2, int ep, const int* __restrict__ flag,
    const unsigned short* __restrict__ Worig)
{
    __shared__ unsigned short As[128 * 64];
    __shared__ unsigned short Bs[128 * 64];
    int isbf = flag ? *flag : 1;
    const unsigned short* Wp = (Worig && isbf) ? Worig : W;
    int tid = threadIdx.x;
    int lane = tid & 63, w = tid >> 6;
    int m0 = blockIdx.x * 128, n0 = blockIdx.y * 128;
    int wm = (w >> 1) * 64, wn = (w & 1) * 64;
    int col = lane & 15, quad = lane >> 4;
    int kstart = blockIdx.z * Ksplit;

    f32x4 acc[4][4];
#pragma unroll
    for (int i = 0; i < 4; ++i)
#pragma unroll
        for (int j = 0; j < 4; ++j)
            acc[i][j] = (f32x4){0.f, 0.f, 0.f, 0.f};

    for (int kt = kstart; kt < kstart + Ksplit; kt += 64) {
#pragma unroll
        for (int i = 0; i < 4; ++i) {
            int seg = i * 4 + w;
            int q = seg * 64 + lane;           // 16B-chunk index 0..1023
            int r = q >> 3, cd = q & 7;
            int cs = cd ^ (r & 7);
            gld_lds16(A + (size_t)(m0 + r) * lda + kt + cs * 8, &As[seg * 512]);
            gld_lds16(Wp + (size_t)(n0 + r) * ldw + kt + cs * 8, &Bs[seg * 512]);
        }
        __syncthreads();
#pragma unroll
        for (int ks = 0; ks < 2; ++ks) {
            bf16x8 af[4], bfr[4];
#pragma unroll
            for (int t = 0; t < 4; ++t) {
                int rowA = wm + t * 16 + col;
                int ca = ks * 4 + quad;
                af[t]  = *(const bf16x8*)&As[rowA * 64 + ((ca ^ (rowA & 7)) * 8)];
                int rowB = wn + t * 16 + col;
                bfr[t] = *(const bf16x8*)&Bs[rowB * 64 + ((ca ^ (rowB & 7)) * 8)];
            }
#pragma unroll
            for (int tm = 0; tm < 4; ++tm)
#pragma unroll
                for (int tn = 0; tn < 4; ++tn)
                    acc[tm][tn] = __builtin_amdgcn_mfma_f32_16x16x32_bf16(
                        af[tm], bfr[tn], acc[tm][tn], 0, 0, 0);
        }
        __syncthreads();
    }

    float* Cp = (float*)C + (size_t)blockIdx.z * cSliceStride;
#pragma unroll
    for (int tm = 0; tm < 4; ++tm)
#pragma unroll
        for (int tn = 0; tn < 4; ++tn)
#pragma unroll
            for (int rg = 0; rg < 4; ++rg) {
                int gm = m0 + wm + tm * 16 + quad * 4 + rg;
                int gn = n0 + wn + tn * 16 + col;
                float v = acc[tm][tn][rg];
                if (ep == 0) {
                    Cp[(size_t)gm * ldc + gn] = v;
                } else { // ep == 2: softplus(v+bias) -> bf16
                    v = softplusf_(v + ldin(bias, boff + gn, isbf));
                    ((unsigned short*)C)[(size_t)gm * ldc + gn] = f2bf(v);
                }
            }
}

// ---- 8-phase 256x256 in_proj GEMM (m201 structure, plain HIP) ----
template <int KS, int MH, int RB, int CHK>
__device__ __forceinline__ void g8_phase(
    unsigned baseA, unsigned baseB,
    bf16x8 (&af)[4], bf16x8 (&bfr)[4], f32x4 (&acc)[8][4],
    int doStage, int st_t, int st_isB, int st_ks,
    const unsigned short* srcA, const unsigned short* srcW,
    unsigned short* ldsb, int w)
{
    if (RB) {
#pragma unroll
        for (int j = 0; j < 4; ++j)
            bfr[j] = ds_read128_(baseB + j * 2048 + KS * 1024);
    }
#pragma unroll
    for (int f = 0; f < 4; ++f)
        af[f] = ds_read128_(baseA + MH * 8192 + f * 2048 + KS * 1024);
    if (doStage) {
        const unsigned short* s0 = (st_isB ? srcW : srcA)
            + (size_t)w * 16 * E_ + st_t * 64 + st_ks * 32;
        unsigned short* d0 = ldsb + (st_t & 1) * 32768 + st_isB * 16384
            + w * 1024 + st_ks * 512;
        gld_lds16(s0, d0);
        gld_lds16(s0 + (size_t)8 * 16 * E_, d0 + 8 * 1024);
    }
    __builtin_amdgcn_s_barrier();
    asm volatile("s_waitcnt lgkmcnt(0)" ::: "memory");
    __builtin_amdgcn_sched_barrier(0);
    __builtin_amdgcn_s_setprio(1);
#pragma unroll
    for (int f = 0; f < 4; ++f)
#pragma unroll
        for (int j = 0; j < 4; ++j)
            acc[MH * 4 + f][j] = __builtin_amdgcn_mfma_f32_16x16x32_bf16(
                af[f], bfr[j], acc[MH * 4 + f][j], 0, 0, 0);
    __builtin_amdgcn_s_setprio(0);
    if (CHK == 8) { asm volatile("s_waitcnt vmcnt(8)" ::: "memory"); __builtin_amdgcn_sched_barrier(0); }
    if (CHK == 4) { asm volatile("s_waitcnt vmcnt(4)" ::: "memory"); __builtin_amdgcn_sched_barrier(0); }
    if (CHK == 0) { asm volatile("s_waitcnt vmcnt(0)"  ::: "memory"); __builtin_amdgcn_sched_barrier(0); }
    __builtin_amdgcn_s_barrier();
}

__global__ __launch_bounds__(512) void gemm_inproj8(
    const unsigned short* __restrict__ A,      // [M_, E_] bf16
    const unsigned short* __restrict__ Wbuf,   // converted weights
    const unsigned short* __restrict__ Worig,  // original (bf16 path)
    const int* __restrict__ flag,
    unsigned short* __restrict__ Cx,           // [M_, DI_] bf16
    unsigned short* __restrict__ Cz)           // [M_, DI_] bf16
{
    __shared__ unsigned short lds[65536];      // 2 bufs * (A 16K + B 16K shorts)
    const unsigned short* W = (*flag) ? Worig : Wbuf;
    int tid = threadIdx.x;
    int lane = tid & 63, w = tid >> 6;         // 8 waves
    int wr = w >> 2, wc = w & 3;               // 2(M) x 4(N)
    int col = lane & 15, quad = lane >> 4;

    int flat = blockIdx.y * 16 + blockIdx.x;
    int nn = (flat & 7) * 32 + (flat >> 3);
    int cch = nn >> 5, wi = nn & 31;
    int bx = (cch & 3) * 4 + (wi & 3);
    int by = (cch >> 2) * 8 + (wi >> 2);
    int m0 = bx * 256, n0 = by * 256;

    const unsigned short* srcA = A + (size_t)(m0 + (lane & 15)) * E_ + (lane >> 4) * 8;
    const unsigned short* srcW = W + (size_t)(n0 + (lane & 15)) * E_ + (lane >> 4) * 8;

    unsigned baseA0 = (unsigned)(wr * 8 * 2048 + quad * 256 + col * 16);
    unsigned baseB0 = (unsigned)(32768 + wc * 4 * 2048 + quad * 256 + col * 16);
    unsigned baseA1 = baseA0 + 65536, baseB1 = baseB0 + 65536;

    f32x4 acc[8][4];
#pragma unroll
    for (int i = 0; i < 8; ++i)
#pragma unroll
        for (int j = 0; j < 4; ++j)
            acc[i][j] = (f32x4){0.f, 0.f, 0.f, 0.f};
    bf16x8 af[4], bfr[4];

#define G8STAGE(t_, isB_, ks_) { \
    const unsigned short* s0 = ((isB_) ? srcW : srcA) + (size_t)w * 16 * E_ + (t_) * 64 + (ks_) * 32; \
    unsigned short* d0 = lds + ((t_) & 1) * 32768 + (isB_) * 16384 + w * 1024 + (ks_) * 512; \
    gld_lds16(s0, d0); gld_lds16(s0 + (size_t)8 * 16 * E_, d0 + 8 * 1024); }

    G8STAGE(0, 0, 0) G8STAGE(0, 1, 0) G8STAGE(0, 0, 1) G8STAGE(0, 1, 1)
    G8STAGE(1, 0, 0) G8STAGE(1, 1, 0)
    asm volatile("s_waitcnt vmcnt(8)" ::: "memory");
    __builtin_amdgcn_sched_barrier(0);
    __builtin_amdgcn_s_barrier();

    for (int i = 0; i < 7; ++i) {              // K=1024 -> 16 tiles -> 8 pairs
        int t1 = 2 * i + 1, t2 = 2 * i + 2, t3 = 2 * i + 3;
        g8_phase<0,0,1,-1>(baseA0, baseB0, af, bfr, acc, 1, t1, 0, 1, srcA, srcW, lds, w);
        g8_phase<0,1,0, 8>(baseA0, baseB0, af, bfr, acc, 1, t1, 1, 1, srcA, srcW, lds, w);
        g8_phase<1,0,1,-1>(baseA0, baseB0, af, bfr, acc, 1, t2, 0, 0, srcA, srcW, lds, w);
        g8_phase<1,1,0, 8>(baseA0, baseB0, af, bfr, acc, 1, t2, 1, 0, srcA, srcW, lds, w);
        g8_phase<0,0,1,-1>(baseA1, baseB1, af, bfr, acc, 1, t2, 0, 1, srcA, srcW, lds, w);
        g8_phase<0,1,0, 8>(baseA1, baseB1, af, bfr, acc, 1, t2, 1, 1, srcA, srcW, lds, w);
        g8_phase<1,0,1,-1>(baseA1, baseB1, af, bfr, acc, 1, t3, 0, 0, srcA, srcW, lds, w);
        g8_phase<1,1,0, 8>(baseA1, baseB1, af, bfr, acc, 1, t3, 1, 0, srcA, srcW, lds, w);
    }
    g8_phase<0,0,1,-1>(baseA0, baseB0, af, bfr, acc, 1, 15, 0, 1, srcA, srcW, lds, w);
    g8_phase<0,1,0, 8>(baseA0, baseB0, af, bfr, acc, 1, 15, 1, 1, srcA, srcW, lds, w);
    g8_phase<1,0,1,-1>(baseA0, baseB0, af, bfr, acc, 0, 0, 0, 0, srcA, srcW, lds, w);
    g8_phase<1,1,0, 4>(baseA0, baseB0, af, bfr, acc, 0, 0, 0, 0, srcA, srcW, lds, w);
    g8_phase<0,0,1,-1>(baseA1, baseB1, af, bfr, acc, 0, 0, 0, 0, srcA, srcW, lds, w);
    g8_phase<0,1,0, 0>(baseA1, baseB1, af, bfr, acc, 0, 0, 0, 0, srcA, srcW, lds, w);
    g8_phase<1,0,1,-1>(baseA1, baseB1, af, bfr, acc, 0, 0, 0, 0, srcA, srcW, lds, w);
    g8_phase<1,1,0,-1>(baseA1, baseB1, af, bfr, acc, 0, 0, 0, 0, srcA, srcW, lds, w);

    unsigned short* dst = (n0 < DI_) ? Cx : Cz;
    int nb = (n0 < DI_) ? n0 : n0 - DI_;
#pragma unroll
    for (int tm = 0; tm < 8; ++tm)
#pragma unroll
        for (int tn = 0; tn < 4; ++tn)
#pragma unroll
            for (int rg = 0; rg < 4; ++rg) {
                int gm = m0 + wr * 128 + tm * 16 + quad * 4 + rg;
                int gn = nb + wc * 64 + tn * 16 + col;
                dst[(size_t)gm * DI_ + gn] = f2bf(acc[tm][tn][rg]);
            }
#undef G8STAGE
}

// reduce 8 x_proj split-K partials -> xdbl fp32 [M,96] + dt16 bf16 [M,64]
__global__ __launch_bounds__(256) void xproj_reduce(
    const float* __restrict__ part, float* __restrict__ xdbl,
    unsigned short* __restrict__ dt16)
{
    int i = blockIdx.x * 256 + threadIdx.x;   // M_*128
    int r = i >> 7, c = i & 127;
    float v = 0.f;
#pragma unroll
    for (int s = 0; s < 8; ++s) v += part[(size_t)s * (M_ * 128) + i];
    if (c < NXD_) xdbl[(size_t)r * NXD_ + c] = v;
    if (c < DTR_) dt16[(size_t)r * DTR_ + c] = f2bf(v);
}

// transpose conv weights to fp32 [DC][DI] + bias fp32 [DI] (per layer)
__global__ __launch_bounds__(256) void conv_prep(
    const void* __restrict__ cw, size_t cwoff, const void* __restrict__ cb,
    size_t cboff, float* __restrict__ cwT, float* __restrict__ cbF,
    const int* __restrict__ flag)
{
    int isbf = *flag;
    int d = blockIdx.x * 256 + threadIdx.x;   // 0..DI_-1
#pragma unroll
    for (int k = 0; k < DC_; ++k)
        cwT[k * DI_ + d] = ldin(cw, cwoff + (size_t)d * DC_ + k, isbf);
    cbF[d] = ldin(cb, cboff + d, isbf);
}

// causal depthwise conv + bias + SiLU, vectorized: 8 channels x 4 timesteps
#define CT_ 4
__global__ __launch_bounds__(256) void conv_silu_v(
    const unsigned short* __restrict__ xcr16, const float* __restrict__ cwT,
    const float* __restrict__ cbF, unsigned short* __restrict__ xc16)
{
    int g = blockIdx.x;                       // row group: rows g*4..g*4+3
    int bl0 = g * CT_;
    int l0 = bl0 & (L_ - 1);                  // within-batch (L divisible by 4)
    int d = threadIdx.x * 8;                  // 8 channels

    float w[DC_][8], bias[8];
#pragma unroll
    for (int k = 0; k < DC_; ++k) {
        *(float4*)&w[k][0] = *(const float4*)&cwT[k * DI_ + d];
        *(float4*)&w[k][4] = *(const float4*)&cwT[k * DI_ + d + 4];
    }
    *(float4*)&bias[0] = *(const float4*)&cbF[d];
    *(float4*)&bias[4] = *(const float4*)&cbF[d + 4];

    float xr[DC_ - 1 + CT_][8];               // rows l0-3 .. l0+3
#pragma unroll
    for (int r = 0; r < DC_ - 1 + CT_; ++r) {
        int l = l0 - (DC_ - 1) + r;
        if (l >= 0) {
            bf16x8 v = *(const bf16x8*)&xcr16[(size_t)(bl0 - (DC_ - 1) + r) * DI_ + d];
#pragma unroll
            for (int j = 0; j < 8; ++j) xr[r][j] = bf2f((unsigned short)v[j]);
        } else {
#pragma unroll
            for (int j = 0; j < 8; ++j) xr[r][j] = 0.f;
        }
    }

#pragma unroll
    for (int t = 0; t < CT_; ++t) {
        float acc[8];
#pragma unroll
        for (int j = 0; j < 8; ++j) acc[j] = bias[j];
#pragma unroll
        for (int k = 0; k < DC_; ++k)
#pragma unroll
            for (int j = 0; j < 8; ++j)
                acc[j] = fmaf(w[k][j], xr[t + k][j], acc[j]);
        bf16x8 ov;
#pragma unroll
        for (int j = 0; j < 8; ++j) {
            float s = acc[j] * sigmoidf_(acc[j]);
            ov[j] = (short)f2bf(s);
        }
        *(bf16x8*)&xc16[(size_t)(bl0 + t) * DI_ + d] = ov;
    }
}

// pass1 (split-state): 2 threads per (b,d,chunk), 8 states each.
// sub = lane bit 5 so partner threads share a wave. Grid (32, NCH) = 2048
// blocks -> 8 blocks/CU -> 100% occupancy ceiling (was 50% at 1 thread/ch).
__global__ __launch_bounds__(256) void scan_part1(
    const unsigned short* __restrict__ dl16, const unsigned short* __restrict__ xc16,
    const float* __restrict__ xdbl,
    const void* __restrict__ A_log, size_t aoff,
    float* __restrict__ sumdbuf, float* __restrict__ scrS,
    const int* __restrict__ flags, int layer)
{
    int isbf = flags[0], fast = flags[1 + layer];
    __shared__ float bs[LC_][16];
    int c = blockIdx.y;
    int b = blockIdx.x >> 4;
    int d0 = (blockIdx.x & 15) << 7;
    int lane = threadIdx.x & 63, w = threadIdx.x >> 6;
    int sub = (lane >> 5) & 1;
    int d = d0 + w * 32 + (lane & 31);
    for (int i = threadIdx.x; i < LC_ * 16; i += 256) {
        int l = i >> 4, n = i & 15;
        bs[l][n] = xdbl[((size_t)b * L_ + c * LC_ + l) * NXD_ + DTR_ + n];
    }
    __syncthreads();
    float a2[8];
#pragma unroll
    for (int j = 0; j < 8; ++j)
        a2[j] = -expf_(ldin(A_log, aoff + (size_t)d * DS_ + sub * 8 + j, isbf)) * LOG2E_;
    float a2r0 = -expf_(ldin(A_log, aoff + (size_t)d * DS_, isbf)) * LOG2E_;
    float s[8] = {};
    float sumd = 0.f;
    const unsigned short* dp = dl16 + ((size_t)b * L_ + c * LC_) * DI_ + d;
    const unsigned short* up = xc16 + ((size_t)b * L_ + c * LC_) * DI_ + d;
    for (int l = 0; l < LC_; ++l) {
        float dv = bf2f(dp[(size_t)l * DI_]);
        float u  = bf2f(up[(size_t)l * DI_]);
        sumd += dv;
        float dvu = dv * u;
        float e[8];
        expvec8(fast, sub, dv, a2r0, a2, e);
        float4 b0 = *(const float4*)&bs[l][sub * 8];
        float4 b1 = *(const float4*)&bs[l][sub * 8 + 4];
        float bv[8] = {b0.x, b0.y, b0.z, b0.w, b1.x, b1.y, b1.z, b1.w};
#pragma unroll
        for (int j = 0; j < 8; ++j)
            s[j] = fmaf(e[j], s[j], dvu * bv[j]);
    }
    int g = b * DI_ + d;
    if (sub == 0) sumdbuf[(size_t)c * (B_ * DI_) + g] = sumd;
    size_t base = ((size_t)c * (B_ * DI_) + g) * 16 + sub * 8;
    *(float4*)&scrS[base]     = make_float4(s[0], s[1], s[2], s[3]);
    *(float4*)&scrS[base + 4] = make_float4(s[4], s[5], s[6], s[7]);
}

// sequential combine: scrS[c] becomes the state ENTERING chunk c.
__global__ __launch_bounds__(256) void scan_combine(
    const float* __restrict__ sumdbuf, float* __restrict__ scrS,
    const void* __restrict__ A_log, size_t aoff, const int* __restrict__ flags)
{
    int isbf = flags[0];
    int t = blockIdx.x * 256 + threadIdx.x;    // g*16+n
    int g = t >> 4, n = t & 15;
    int d = g & (DI_ - 1);
    float a2 = -expf_(ldin(A_log, aoff + (size_t)d * DS_ + n, isbf)) * LOG2E_;
    float sd[NCH_], sl[NCH_];
#pragma unroll
    for (int c = 0; c < NCH_; ++c) {
        sd[c] = sumdbuf[(size_t)c * (B_ * DI_) + g];
        sl[c] = scrS[(size_t)c * (B_ * DI_ * 16) + t];
    }
    float s = 0.f;
#pragma unroll
    for (int c = 0; c < NCH_; ++c) {
        float P = __builtin_amdgcn_exp2f(a2 * sd[c]);
        float nxt = fmaf(P, s, sl[c]);
        scrS[(size_t)c * (B_ * DI_ * 16) + t] = s;
        s = nxt;
    }
}

// pass2 (split-state): re-run chunk with correct init; per-timestep y is the
// sum of both subs' partials via one intra-wave shfl; sub0 gates + stores.
__global__ __launch_bounds__(256) void scan_part2(
    const unsigned short* __restrict__ dl16, unsigned short* __restrict__ xc16,
    const float* __restrict__ xdbl, const unsigned short* __restrict__ z,
    const void* __restrict__ A_log, size_t aoff,
    const void* __restrict__ Dskip, size_t doff,
    const float* __restrict__ scrS, const int* __restrict__ flags, int layer)
{
    int isbf = flags[0], fast = flags[1 + layer];
    __shared__ float bs[LC_][32];              // [l][n]=B, [l][16+n]=C
    int c = blockIdx.y;
    int b = blockIdx.x >> 4;
    int d0 = (blockIdx.x & 15) << 7;
    int lane = threadIdx.x & 63, w = threadIdx.x >> 6;
    int sub = (lane >> 5) & 1;
    int d = d0 + w * 32 + (lane & 31);
    for (int i = threadIdx.x; i < LC_ * 32; i += 256) {
        int l = i >> 5, n = i & 31;
        bs[l][n] = xdbl[((size_t)b * L_ + c * LC_ + l) * NXD_ + DTR_ + n];
    }
    __syncthreads();
    float a2[8];
#pragma unroll
    for (int j = 0; j < 8; ++j)
        a2[j] = -expf_(ldin(A_log, aoff + (size_t)d * DS_ + sub * 8 + j, isbf)) * LOG2E_;
    float a2r0 = -expf_(ldin(A_log, aoff + (size_t)d * DS_, isbf)) * LOG2E_;
    float Dv = ldin(Dskip, doff + d, isbf);
    int g = b * DI_ + d;
    size_t sbase = ((size_t)c * (B_ * DI_) + g) * 16 + sub * 8;
    float s[8];
    {
        float4 sv0 = *(const float4*)&scrS[sbase];
        float4 sv1 = *(const float4*)&scrS[sbase + 4];
        s[0] = sv0.x; s[1] = sv0.y; s[2] = sv0.z; s[3] = sv0.w;
        s[4] = sv1.x; s[5] = sv1.y; s[6] = sv1.z; s[7] = sv1.w;
    }

    const unsigned short* dp = dl16 + ((size_t)b * L_ + c * LC_) * DI_ + d;
    unsigned short* up = xc16 + ((size_t)b * L_ + c * LC_) * DI_ + d;
    const unsigned short* zp = z + ((size_t)b * L_ + c * LC_) * DI_ + d;
    for (int l = 0; l < LC_; ++l) {
        float dv = bf2f(dp[(size_t)l * DI_]);
        float u  = bf2f(up[(size_t)l * DI_]);
        float dvu = dv * u;
        float e[8];
        expvec8(fast, sub, dv, a2r0, a2, e);
        float4 b0 = *(const float4*)&bs[l][sub * 8];
        float4 b1 = *(const float4*)&bs[l][sub * 8 + 4];
        float4 c0 = *(const float4*)&bs[l][16 + sub * 8];
        float4 c1 = *(const float4*)&bs[l][16 + sub * 8 + 4];
        float bv[8] = {b0.x, b0.y, b0.z, b0.w, b1.x, b1.y, b1.z, b1.w};
        float cv[8] = {c0.x, c0.y, c0.z, c0.w, c1.x, c1.y, c1.z, c1.w};
        float y = 0.f;
#pragma unroll
        for (int j = 0; j < 8; ++j) {
            s[j] = fmaf(e[j], s[j], dvu * bv[j]);
            y = fmaf(s[j], cv[j], y);
        }
        y += __shfl_xor(y, 32, 64);
        if (sub == 0) {
            float zv = bf2f(zp[(size_t)l * DI_]);
            up[(size_t)l * DI_] = f2bf((y + u * Dv) * (zv * sigmoidf_(zv)));
        }
    }
}

// h = rmsnorm(y0 + y1 + h) * norm_w ; also bf16 copy; optionally final out
__global__ __launch_bounds__(256) void rmsnorm_kernel(
    const float* __restrict__ y0, const float* __restrict__ y1,
    float* __restrict__ h, unsigned short* __restrict__ h16,
    const void* __restrict__ nw, size_t nwoff, void* __restrict__ out,
    int write_out, const int* __restrict__ flag)
{
    int isbf = *flag;
    __shared__ float red[4];
    int row = blockIdx.x;
    float* hp = h + (size_t)row * E_;
    float v[4]; float ss = 0.f;
#pragma unroll
    for (int i = 0; i < 4; ++i) {
        int e = threadIdx.x + i * 256;
        size_t idx = (size_t)row * E_ + e;
        v[i] = y0[idx] + y1[idx] + hp[e];
        ss += v[i] * v[i];
    }
#pragma unroll
    for (int off = 1; off < 64; off <<= 1) ss += __shfl_xor(ss, off, 64);
    if ((threadIdx.x & 63) == 0) red[threadIdx.x >> 6] = ss;
    __syncthreads();
    ss = red[0] + red[1] + red[2] + red[3];
    float scale = rsqrtf(ss * (1.f / E_) + 1e-6f);
#pragma unroll
    for (int i = 0; i < 4; ++i) {
        int e = threadIdx.x + i * 256;
        float hv = v[i] * scale * ldin(nw, nwoff + e, isbf);
        hp[e] = hv;
        h16[(size_t)row * E_ + e] = f2bf(hv);
        if (write_out) {
            size_t oi = (size_t)row * E_ + e;
            if (isbf) ((unsigned short*)out)[oi] = f2bf(hv);
            else      ((float*)out)[oi] = hv;
        }
    }
}

extern "C" void kernel_launch(void* const* d_in, const int* in_sizes, int n_in,
                              void* d_out, int out_size, void* d_ws, size_t ws_size,
                              hipStream_t stream)
{
    const void* x    = d_in[0];
    const void* pos  = d_in[1];
    const void* inw  = d_in[2];
    const void* cw   = d_in[3];
    const void* cb   = d_in[4];
    const void* xw   = d_in[5];
    const void* dtw  = d_in[6];
    const void* dtb  = d_in[7];
    const void* alog = d_in[8];
    const void* dsk  = d_in[9];
    const void* ow   = d_in[10];
    const void* nw   = d_in[11];

    float* ws = (float*)d_ws;
    float* h      = ws;                                        // 4,194,304 f
    unsigned short* h16  = (unsigned short*)(ws + 4194304);    // 2,097,152 f
    unsigned short* z16  = (unsigned short*)(ws + 6291456);    // 4,194,304 f
    unsigned short* xc16 = (unsigned short*)(ws + 10485760);   // 4,194,304 f
    float* D      = ws + 14680064;                             // 8,388,608 f (delta16 -> yout x2)
    float* R      = ws + 23068672;                             // 4,194,304 f (xcr16/xp_part/scrS)
    float* xdbl   = ws + 27262976;                             //   393,216 f
    unsigned short* dt16 = (unsigned short*)(ws + 27656192);   //   131,072 f
    float* sumd   = ws + 27787264;                             //   262,144 f
    unsigned short* wbuf = (unsigned short*)(ws + 28049408);   // 3,342,336 f
    int* flags    = (int*)(ws + 31391744);
    // total ~125.6 MB (same proven footprint)

    unsigned short* xcr16 = (unsigned short*)R;    // in_proj xc_raw (bf16)
    float* xp_part = R;                            // x_proj split-K partials
    float* scrS    = R;                            // scan chunk states (16.8 MB)
    unsigned short* dl16 = (unsigned short*)D;     // delta bf16 (dead before yout)
    float* yout0 = D;
    float* yout1 = D + (size_t)M_ * E_;
    // conv weight transpose lives in sumd (dead until scan_part1)
    float* cwT = sumd;                             // DC_*DI_ = 8192 f
    float* cbF = sumd + DC_ * DI_;                 // DI_ = 2048 f

    detect_kernel<<<1, 256, 0, stream>>>((const unsigned*)x, flags);
    chk_alog<<<NL_ * DI_ * DS_ / 256, 256, 0, stream>>>(alog, flags);
    add_pos_kernel<<<M_ * E_ / 256, 256, 0, stream>>>(x, pos, h, h16, flags);

    for (int layer = 0; layer < NL_; ++layer) {
        const unsigned short* inws = (const unsigned short*)inw + (size_t)layer * 2 * DI_ * E_;
        const unsigned short* dtws = (const unsigned short*)dtw + (size_t)layer * DI_ * DTR_;
        const unsigned short* ows  = (const unsigned short*)ow  + (size_t)layer * E_ * DI_;

        cvt_layer_kernel<<<WB_TOT_ / 256, 256, 0, stream>>>(
            inw, xw, dtw, ow, layer, wbuf, flags);
        conv_prep<<<DI_ / 256, 256, 0, stream>>>(
            cw, (size_t)layer * DI_ * DC_, cb, (size_t)layer * DI_, cwT, cbF, flags);

        // fused in_proj: [xc_raw | z] = h @ in_proj^T  (256x256 8-phase)
        gemm_inproj8<<<dim3(M_ / 256, 2 * DI_ / 256, 1), 512, 0, stream>>>(
            h16, wbuf + WB_IN_, inws, flags, xcr16, z16);
        // xc = silu(conv(xc_raw)+cb), vectorized 8ch x 4t per thread
        conv_silu_v<<<M_ / CT_, 256, 0, stream>>>(xcr16, cwT, cbF, xc16);
        // x_dbl partials: split-K=8 (256 blocks), then reduce -> xdbl + dt16
        gemm_mfma<<<dim3(M_ / 128, 1, 8), 256, 0, stream>>>(
            xc16, DI_, wbuf + WB_XW_, DI_, xp_part, 128, DI_ / 8, (size_t)M_ * 128,
            nullptr, 0, nullptr, 0, flags, nullptr);
        xproj_reduce<<<M_ * 128 / 256, 256, 0, stream>>>(xp_part, xdbl, dt16);
        // delta = softplus(dt @ dt_proj^T + dtb) -> dl16 (bf16)
        gemm_mfma<<<dim3(M_ / 128, DI_ / 128, 1), 256, 0, stream>>>(
            dt16, DTR_, wbuf + WB_DTW_, DTR_, dl16, DI_, DTR_, 0,
            dtb, (size_t)layer * DI_, nullptr, 2, flags, dtws);
        // chunked scan (split-state: 2 threads/channel); y in place into xc16
        scan_part1<<<dim3(32, NCH_), 256, 0, stream>>>(
            dl16, xc16, xdbl, alog, (size_t)layer * DI_ * DS_, sumd, scrS, flags, layer);
        scan_combine<<<B_ * DI_ * DS_ / 256, 256, 0, stream>>>(
            sumd, scrS, alog, (size_t)layer * DI_ * DS_, flags);
        scan_part2<<<dim3(32, NCH_), 256, 0, stream>>>(
            dl16, xc16, xdbl, z16, alog, (size_t)layer * DI_ * DS_,
            dsk, (size_t)layer * DI_, scrS, flags, layer);
        // yout = y @ out_proj^T, split-K=2 (512 blocks) -> yout partials
        gemm_mfma<<<dim3(M_ / 128, E_ / 128, 2), 256, 0, stream>>>(
            xc16, DI_, wbuf + WB_OW_, DI_, yout0, E_, DI_ / 2, (size_t)M_ * E_,
            nullptr, 0, nullptr, 0, flags, ows);
        // h = rmsnorm(yout0 + yout1 + h); emit output on last layer
        rmsnorm_kernel<<<M_, 256, 0, stream>>>(
            yout0, yout1, h, h16, nw, (size_t)layer * E_, d_out,
            layer == NL_ - 1 ? 1 : 0, flags);
    }
}

// Round 7
// 552.966 us; speedup vs baseline: 1.1693x; 1.0549x over previous
//
#include <hip/hip_runtime.h>

// MambaTower: B=2, L=2048, E=1024, NL=2, DI=2048, DS=16, DC=4, DTR=64
#define B_   2
#define L_   2048
#define E_   1024
#define NL_  2
#define DI_  2048
#define DS_  16
#define DC_  4
#define DTR_ 64
#define NXD_ 96            // DTR + 2*DS
#define M_   (B_ * L_)     // 4096 rows
#define NCH_ 64            // scan chunks
#define LC_  32            // timesteps per chunk

typedef __attribute__((ext_vector_type(8))) short bf16x8;
typedef __attribute__((ext_vector_type(4))) float f32x4;

__device__ __forceinline__ float bf2f(unsigned short u) {
    return __uint_as_float(((unsigned)u) << 16);
}
__device__ __forceinline__ unsigned short f2bf(float f) {
    unsigned u = __float_as_uint(f);
    u += 0x7fff + ((u >> 16) & 1);
    return (unsigned short)(u >> 16);
}

#define LOG2E_ 1.44269504f
#define LN2_   0.69314718f

// hardware-transcendental forms: v_exp_f32 computes 2^x, v_log_f32 computes log2(x)
__device__ __forceinline__ float sigmoidf_(float x) {
    return __builtin_amdgcn_rcpf(1.f + __builtin_amdgcn_exp2f(-x * LOG2E_));
}
__device__ __forceinline__ float softplusf_(float x) {
    float e = __builtin_amdgcn_exp2f(x * LOG2E_);
    float s = LN2_ * __builtin_amdgcn_logf(1.f + e);
    return x > 15.f ? x : s;
}
__device__ __forceinline__ float expf_(float x) {       // e^x
    return __builtin_amdgcn_exp2f(x * LOG2E_);
}
__device__ __forceinline__ float ldin(const void* p, size_t i, int isbf) {
    return isbf ? bf2f(((const unsigned short*)p)[i]) : ((const float*)p)[i];
}
__device__ __forceinline__ void gld_lds16(const unsigned short* g, unsigned short* l) {
    __builtin_amdgcn_global_load_lds(
        (const __attribute__((address_space(1))) unsigned int*)g,
        (__attribute__((address_space(3))) unsigned int*)l, 16, 0, 0);
}
// opaque LDS read (compiler can't alias with global_load_lds; paired with
// explicit lgkmcnt(0)+sched_barrier before use)
__device__ __forceinline__ bf16x8 ds_read128_(unsigned byteoff) {
    bf16x8 r;
    asm volatile("ds_read_b128 %0, %1" : "=&v"(r) : "v"(byteoff));
    return r;
}

// build e[n] = exp(dv*a[n]) given a2[n] = a[n]*log2e; fast path uses
// a[n] = (n+1)*a[0] (validated by chk_alog) -> 1 exp + 15 muls
__device__ __forceinline__ void expvec(int fast, float dv, const float* a2, float* e) {
    if (fast) {
        float p1 = __builtin_amdgcn_exp2f(dv * a2[0]);
        float p2 = p1 * p1, p4 = p2 * p2, p8 = p4 * p4;
        e[0] = p1;        e[1] = p2;        e[2] = p2 * p1;   e[3] = p4;
        e[4] = p4 * p1;   e[5] = p4 * p2;   e[6] = e[5] * p1; e[7] = p8;
        e[8] = p8 * p1;   e[9] = p8 * p2;   e[10] = e[9] * p1; e[11] = p8 * p4;
        e[12] = e[11] * p1; e[13] = e[11] * p2; e[14] = e[13] * p1; e[15] = p8 * p8;
    } else {
#pragma unroll
        for (int n = 0; n < 16; ++n) e[n] = __builtin_amdgcn_exp2f(dv * a2[n]);
    }
}

// flags[0]=dtype(1=bf16), flags[1+layer]=A_log linear-structure fast flag
__global__ __launch_bounds__(256) void detect_kernel(const unsigned* __restrict__ x,
                                                     int* __restrict__ flags)
{
    __shared__ int cnt;
    if (threadIdx.x == 0) cnt = 0;
    __syncthreads();
    unsigned v = x[threadIdx.x];
    int e = (v >> 7) & 0xFF;
    if (e >= 90 && e <= 140) atomicAdd(&cnt, 1);
    __syncthreads();
    if (threadIdx.x == 0) {
        flags[0] = (cnt >= 192) ? 1 : 0;
        flags[1] = 1;
        flags[2] = 1;
    }
}

// validate a[n] ~= (n+1)*a[0] for every (layer,d); clear fast flag on fail
__global__ __launch_bounds__(256) void chk_alog(
    const void* __restrict__ alog, int* __restrict__ flags)
{
    int isbf = flags[0];
    int i = blockIdx.x * 256 + threadIdx.x;      // NL*DI*DS
    int layer = i / (DI_ * DS_);
    int n = i & (DS_ - 1);
    float a  = -expf_(ldin(alog, i, isbf));
    float a0 = -expf_(ldin(alog, i - n, isbf));
    float want = (n + 1) * a0;
    if (fabsf(a - want) > 0.02f * fabsf(want))
        atomicAnd(&flags[1 + layer], 0);
}

// convert weights to bf16 into wbuf (xw padded 96->128 rows). When input is
// already bf16 the in/dt/ow copies are identity -> consumers read the input
// tensors directly and we only build the padded xw block here.
#define WB_IN_  0
#define WB_XW_  4194304
#define WB_DTW_ 4456448
#define WB_OW_  4587520
#define WB_TOT_ 6684672
__global__ __launch_bounds__(256) void cvt_layer_kernel(
    const void* __restrict__ inw, const void* __restrict__ xw,
    const void* __restrict__ dtw, const void* __restrict__ ow,
    int layer, unsigned short* __restrict__ wbuf, const int* __restrict__ flag)
{
    int isbf = *flag;
    int i = blockIdx.x * 256 + threadIdx.x;    // 0..WB_TOT_-1
    if (isbf && (i < WB_XW_ || i >= WB_DTW_)) return;   // identity regions skipped
    unsigned short v;
    if (i < WB_XW_) {
        v = isbf ? ((const unsigned short*)inw)[(size_t)layer * 2 * DI_ * E_ + i]
                 : f2bf(((const float*)inw)[(size_t)layer * 2 * DI_ * E_ + i]);
    } else if (i < WB_DTW_) {
        int j = i - WB_XW_; int r = j >> 11, k = j & (DI_ - 1);
        v = (r < NXD_)
          ? (isbf ? ((const unsigned short*)xw)[(size_t)layer * NXD_ * DI_ + (size_t)r * DI_ + k]
                  : f2bf(((const float*)xw)[(size_t)layer * NXD_ * DI_ + (size_t)r * DI_ + k]))
          : (unsigned short)0;
    } else if (i < WB_OW_) {
        int j = i - WB_DTW_;
        v = isbf ? ((const unsigned short*)dtw)[(size_t)layer * DI_ * DTR_ + j]
                 : f2bf(((const float*)dtw)[(size_t)layer * DI_ * DTR_ + j]);
    } else {
        int j = i - WB_OW_;
        v = isbf ? ((const unsigned short*)ow)[(size_t)layer * E_ * DI_ + j]
                 : f2bf(((const float*)ow)[(size_t)layer * E_ * DI_ + j]);
    }
    wbuf[i] = v;
}

// h = x + pos (fp32 + bf16 copies)
__global__ __launch_bounds__(256) void add_pos_kernel(
    const void* __restrict__ x, const void* __restrict__ pos,
    float* __restrict__ h, unsigned short* __restrict__ h16,
    const int* __restrict__ flag)
{
    int isbf = *flag;
    int i = blockIdx.x * 256 + threadIdx.x;
    float v = ldin(x, i, isbf) + ldin(pos, i & (L_ * E_ - 1), isbf);
    h[i] = v;
    h16[i] = f2bf(v);
}

// ---- MFMA GEMM: C[M,N] = A[M,K](bf16) * W[N,K](bf16)^T ----
// 128x128 tile, BK=64, 256 threads = 4 waves (2x2 of 64x64).
// XOR-swizzled LDS chunk layout (0 bank conflicts, coalesced staging).
// blockIdx.z = split-K slice; ep0 partials advance C by z*cSliceStride.
// ep: 0=fp32 store, 2=softplus(v+bias[n]) -> bf16 store
// Worig: when non-null and *flag (bf16 inputs), use original weight tensor.
__global__ __launch_bounds__(256) void gemm_mfma(
    const unsigned short* __restrict__ A, int lda,
    const unsigned short* __restrict__ W, int ldw,
    void* __restrict__ C, int ldc, int Ksplit, size_t cSliceStride,
    const void* __restrict__ bias, size_t boff,
    void* __restrict__ C2, int ep, const int* __restrict__ flag,
    const unsigned short* __restrict__ Worig)
{
    __shared__ unsigned short As[128 * 64];
    __shared__ unsigned short Bs[128 * 64];
    int isbf = flag ? *flag : 1;
    const unsigned short* Wp = (Worig && isbf) ? Worig : W;
    int tid = threadIdx.x;
    int lane = tid & 63, w = tid >> 6;
    int m0 = blockIdx.x * 128, n0 = blockIdx.y * 128;
    int wm = (w >> 1) * 64, wn = (w & 1) * 64;
    int col = lane & 15, quad = lane >> 4;
    int kstart = blockIdx.z * Ksplit;

    f32x4 acc[4][4];
#pragma unroll
    for (int i = 0; i < 4; ++i)
#pragma unroll
        for (int j = 0; j < 4; ++j)
            acc[i][j] = (f32x4){0.f, 0.f, 0.f, 0.f};

    for (int kt = kstart; kt < kstart + Ksplit; kt += 64) {
#pragma unroll
        for (int i = 0; i < 4; ++i) {
            int seg = i * 4 + w;
            int q = seg * 64 + lane;           // 16B-chunk index 0..1023
            int r = q >> 3, cd = q & 7;
            int cs = cd ^ (r & 7);
            gld_lds16(A + (size_t)(m0 + r) * lda + kt + cs * 8, &As[seg * 512]);
            gld_lds16(Wp + (size_t)(n0 + r) * ldw + kt + cs * 8, &Bs[seg * 512]);
        }
        __syncthreads();
#pragma unroll
        for (int ks = 0; ks < 2; ++ks) {
            bf16x8 af[4], bfr[4];
#pragma unroll
            for (int t = 0; t < 4; ++t) {
                int rowA = wm + t * 16 + col;
                int ca = ks * 4 + quad;
                af[t]  = *(const bf16x8*)&As[rowA * 64 + ((ca ^ (rowA & 7)) * 8)];
                int rowB = wn + t * 16 + col;
                bfr[t] = *(const bf16x8*)&Bs[rowB * 64 + ((ca ^ (rowB & 7)) * 8)];
            }
#pragma unroll
            for (int tm = 0; tm < 4; ++tm)
#pragma unroll
                for (int tn = 0; tn < 4; ++tn)
                    acc[tm][tn] = __builtin_amdgcn_mfma_f32_16x16x32_bf16(
                        af[tm], bfr[tn], acc[tm][tn], 0, 0, 0);
        }
        __syncthreads();
    }

    float* Cp = (float*)C + (size_t)blockIdx.z * cSliceStride;
#pragma unroll
    for (int tm = 0; tm < 4; ++tm)
#pragma unroll
        for (int tn = 0; tn < 4; ++tn)
#pragma unroll
            for (int rg = 0; rg < 4; ++rg) {
                int gm = m0 + wm + tm * 16 + quad * 4 + rg;
                int gn = n0 + wn + tn * 16 + col;
                float v = acc[tm][tn][rg];
                if (ep == 0) {
                    Cp[(size_t)gm * ldc + gn] = v;
                } else { // ep == 2: softplus(v+bias) -> bf16
                    v = softplusf_(v + ldin(bias, boff + gn, isbf));
                    ((unsigned short*)C)[(size_t)gm * ldc + gn] = f2bf(v);
                }
            }
}

// ---- 8-phase 256x256 in_proj GEMM (m201 structure, plain HIP) ----
template <int KS, int MH, int RB, int CHK>
__device__ __forceinline__ void g8_phase(
    unsigned baseA, unsigned baseB,
    bf16x8 (&af)[4], bf16x8 (&bfr)[4], f32x4 (&acc)[8][4],
    int doStage, int st_t, int st_isB, int st_ks,
    const unsigned short* srcA, const unsigned short* srcW,
    unsigned short* ldsb, int w)
{
    if (RB) {
#pragma unroll
        for (int j = 0; j < 4; ++j)
            bfr[j] = ds_read128_(baseB + j * 2048 + KS * 1024);
    }
#pragma unroll
    for (int f = 0; f < 4; ++f)
        af[f] = ds_read128_(baseA + MH * 8192 + f * 2048 + KS * 1024);
    if (doStage) {
        const unsigned short* s0 = (st_isB ? srcW : srcA)
            + (size_t)w * 16 * E_ + st_t * 64 + st_ks * 32;
        unsigned short* d0 = ldsb + (st_t & 1) * 32768 + st_isB * 16384
            + w * 1024 + st_ks * 512;
        gld_lds16(s0, d0);
        gld_lds16(s0 + (size_t)8 * 16 * E_, d0 + 8 * 1024);
    }
    __builtin_amdgcn_s_barrier();
    asm volatile("s_waitcnt lgkmcnt(0)" ::: "memory");
    __builtin_amdgcn_sched_barrier(0);
    __builtin_amdgcn_s_setprio(1);
#pragma unroll
    for (int f = 0; f < 4; ++f)
#pragma unroll
        for (int j = 0; j < 4; ++j)
            acc[MH * 4 + f][j] = __builtin_amdgcn_mfma_f32_16x16x32_bf16(
                af[f], bfr[j], acc[MH * 4 + f][j], 0, 0, 0);
    __builtin_amdgcn_s_setprio(0);
    if (CHK == 8) { asm volatile("s_waitcnt vmcnt(8)" ::: "memory"); __builtin_amdgcn_sched_barrier(0); }
    if (CHK == 4) { asm volatile("s_waitcnt vmcnt(4)" ::: "memory"); __builtin_amdgcn_sched_barrier(0); }
    if (CHK == 0) { asm volatile("s_waitcnt vmcnt(0)"  ::: "memory"); __builtin_amdgcn_sched_barrier(0); }
    __builtin_amdgcn_s_barrier();
}

__global__ __launch_bounds__(512) void gemm_inproj8(
    const unsigned short* __restrict__ A,      // [M_, E_] bf16
    const unsigned short* __restrict__ Wbuf,   // converted weights
    const unsigned short* __restrict__ Worig,  // original (bf16 path)
    const int* __restrict__ flag,
    unsigned short* __restrict__ Cx,           // [M_, DI_] bf16
    unsigned short* __restrict__ Cz)           // [M_, DI_] bf16
{
    __shared__ unsigned short lds[65536];      // 2 bufs * (A 16K + B 16K shorts)
    const unsigned short* W = (*flag) ? Worig : Wbuf;
    int tid = threadIdx.x;
    int lane = tid & 63, w = tid >> 6;         // 8 waves
    int wr = w >> 2, wc = w & 3;               // 2(M) x 4(N)
    int col = lane & 15, quad = lane >> 4;

    int flat = blockIdx.y * 16 + blockIdx.x;
    int nn = (flat & 7) * 32 + (flat >> 3);
    int cch = nn >> 5, wi = nn & 31;
    int bx = (cch & 3) * 4 + (wi & 3);
    int by = (cch >> 2) * 8 + (wi >> 2);
    int m0 = bx * 256, n0 = by * 256;

    const unsigned short* srcA = A + (size_t)(m0 + (lane & 15)) * E_ + (lane >> 4) * 8;
    const unsigned short* srcW = W + (size_t)(n0 + (lane & 15)) * E_ + (lane >> 4) * 8;

    unsigned baseA0 = (unsigned)(wr * 8 * 2048 + quad * 256 + col * 16);
    unsigned baseB0 = (unsigned)(32768 + wc * 4 * 2048 + quad * 256 + col * 16);
    unsigned baseA1 = baseA0 + 65536, baseB1 = baseB0 + 65536;

    f32x4 acc[8][4];
#pragma unroll
    for (int i = 0; i < 8; ++i)
#pragma unroll
        for (int j = 0; j < 4; ++j)
            acc[i][j] = (f32x4){0.f, 0.f, 0.f, 0.f};
    bf16x8 af[4], bfr[4];

#define G8STAGE(t_, isB_, ks_) { \
    const unsigned short* s0 = ((isB_) ? srcW : srcA) + (size_t)w * 16 * E_ + (t_) * 64 + (ks_) * 32; \
    unsigned short* d0 = lds + ((t_) & 1) * 32768 + (isB_) * 16384 + w * 1024 + (ks_) * 512; \
    gld_lds16(s0, d0); gld_lds16(s0 + (size_t)8 * 16 * E_, d0 + 8 * 1024); }

    G8STAGE(0, 0, 0) G8STAGE(0, 1, 0) G8STAGE(0, 0, 1) G8STAGE(0, 1, 1)
    G8STAGE(1, 0, 0) G8STAGE(1, 1, 0)
    asm volatile("s_waitcnt vmcnt(8)" ::: "memory");
    __builtin_amdgcn_sched_barrier(0);
    __builtin_amdgcn_s_barrier();

    for (int i = 0; i < 7; ++i) {              // K=1024 -> 16 tiles -> 8 pairs
        int t1 = 2 * i + 1, t2 = 2 * i + 2, t3 = 2 * i + 3;
        g8_phase<0,0,1,-1>(baseA0, baseB0, af, bfr, acc, 1, t1, 0, 1, srcA, srcW, lds, w);
        g8_phase<0,1,0, 8>(baseA0, baseB0, af, bfr, acc, 1, t1, 1, 1, srcA, srcW, lds, w);
        g8_phase<1,0,1,-1>(baseA0, baseB0, af, bfr, acc, 1, t2, 0, 0, srcA, srcW, lds, w);
        g8_phase<1,1,0, 8>(baseA0, baseB0, af, bfr, acc, 1, t2, 1, 0, srcA, srcW, lds, w);
        g8_phase<0,0,1,-1>(baseA1, baseB1, af, bfr, acc, 1, t2, 0, 1, srcA, srcW, lds, w);
        g8_phase<0,1,0, 8>(baseA1, baseB1, af, bfr, acc, 1, t2, 1, 1, srcA, srcW, lds, w);
        g8_phase<1,0,1,-1>(baseA1, baseB1, af, bfr, acc, 1, t3, 0, 0, srcA, srcW, lds, w);
        g8_phase<1,1,0, 8>(baseA1, baseB1, af, bfr, acc, 1, t3, 1, 0, srcA, srcW, lds, w);
    }
    g8_phase<0,0,1,-1>(baseA0, baseB0, af, bfr, acc, 1, 15, 0, 1, srcA, srcW, lds, w);
    g8_phase<0,1,0, 8>(baseA0, baseB0, af, bfr, acc, 1, 15, 1, 1, srcA, srcW, lds, w);
    g8_phase<1,0,1,-1>(baseA0, baseB0, af, bfr, acc, 0, 0, 0, 0, srcA, srcW, lds, w);
    g8_phase<1,1,0, 4>(baseA0, baseB0, af, bfr, acc, 0, 0, 0, 0, srcA, srcW, lds, w);
    g8_phase<0,0,1,-1>(baseA1, baseB1, af, bfr, acc, 0, 0, 0, 0, srcA, srcW, lds, w);
    g8_phase<0,1,0, 0>(baseA1, baseB1, af, bfr, acc, 0, 0, 0, 0, srcA, srcW, lds, w);
    g8_phase<1,0,1,-1>(baseA1, baseB1, af, bfr, acc, 0, 0, 0, 0, srcA, srcW, lds, w);
    g8_phase<1,1,0,-1>(baseA1, baseB1, af, bfr, acc, 0, 0, 0, 0, srcA, srcW, lds, w);

    unsigned short* dst = (n0 < DI_) ? Cx : Cz;
    int nb = (n0 < DI_) ? n0 : n0 - DI_;
#pragma unroll
    for (int tm = 0; tm < 8; ++tm)
#pragma unroll
        for (int tn = 0; tn < 4; ++tn)
#pragma unroll
            for (int rg = 0; rg < 4; ++rg) {
                int gm = m0 + wr * 128 + tm * 16 + quad * 4 + rg;
                int gn = nb + wc * 64 + tn * 16 + col;
                dst[(size_t)gm * DI_ + gn] = f2bf(acc[tm][tn][rg]);
            }
#undef G8STAGE
}

// reduce 8 x_proj split-K partials -> xdbl fp32 [M,96] + dt16 bf16 [M,64]
__global__ __launch_bounds__(256) void xproj_reduce(
    const float* __restrict__ part, float* __restrict__ xdbl,
    unsigned short* __restrict__ dt16)
{
    int i = blockIdx.x * 256 + threadIdx.x;   // M_*128
    int r = i >> 7, c = i & 127;
    float v = 0.f;
#pragma unroll
    for (int s = 0; s < 8; ++s) v += part[(size_t)s * (M_ * 128) + i];
    if (c < NXD_) xdbl[(size_t)r * NXD_ + c] = v;
    if (c < DTR_) dt16[(size_t)r * DTR_ + c] = f2bf(v);
}

// transpose conv weights to fp32 [DC][DI] + bias fp32 [DI] (per layer)
__global__ __launch_bounds__(256) void conv_prep(
    const void* __restrict__ cw, size_t cwoff, const void* __restrict__ cb,
    size_t cboff, float* __restrict__ cwT, float* __restrict__ cbF,
    const int* __restrict__ flag)
{
    int isbf = *flag;
    int d = blockIdx.x * 256 + threadIdx.x;   // 0..DI_-1
#pragma unroll
    for (int k = 0; k < DC_; ++k)
        cwT[k * DI_ + d] = ldin(cw, cwoff + (size_t)d * DC_ + k, isbf);
    cbF[d] = ldin(cb, cboff + d, isbf);
}

// causal depthwise conv + bias + SiLU, vectorized: 8 channels x 4 timesteps
#define CT_ 4
__global__ __launch_bounds__(256) void conv_silu_v(
    const unsigned short* __restrict__ xcr16, const float* __restrict__ cwT,
    const float* __restrict__ cbF, unsigned short* __restrict__ xc16)
{
    int g = blockIdx.x;                       // row group: rows g*4..g*4+3
    int bl0 = g * CT_;
    int l0 = bl0 & (L_ - 1);                  // within-batch (L divisible by 4)
    int d = threadIdx.x * 8;                  // 8 channels

    float w[DC_][8], bias[8];
#pragma unroll
    for (int k = 0; k < DC_; ++k) {
        *(float4*)&w[k][0] = *(const float4*)&cwT[k * DI_ + d];
        *(float4*)&w[k][4] = *(const float4*)&cwT[k * DI_ + d + 4];
    }
    *(float4*)&bias[0] = *(const float4*)&cbF[d];
    *(float4*)&bias[4] = *(const float4*)&cbF[d + 4];

    float xr[DC_ - 1 + CT_][8];               // rows l0-3 .. l0+3
#pragma unroll
    for (int r = 0; r < DC_ - 1 + CT_; ++r) {
        int l = l0 - (DC_ - 1) + r;
        if (l >= 0) {
            bf16x8 v = *(const bf16x8*)&xcr16[(size_t)(bl0 - (DC_ - 1) + r) * DI_ + d];
#pragma unroll
            for (int j = 0; j < 8; ++j) xr[r][j] = bf2f((unsigned short)v[j]);
        } else {
#pragma unroll
            for (int j = 0; j < 8; ++j) xr[r][j] = 0.f;
        }
    }

#pragma unroll
    for (int t = 0; t < CT_; ++t) {
        float acc[8];
#pragma unroll
        for (int j = 0; j < 8; ++j) acc[j] = bias[j];
#pragma unroll
        for (int k = 0; k < DC_; ++k)
#pragma unroll
            for (int j = 0; j < 8; ++j)
                acc[j] = fmaf(w[k][j], xr[t + k][j], acc[j]);
        bf16x8 ov;
#pragma unroll
        for (int j = 0; j < 8; ++j) {
            float s = acc[j] * sigmoidf_(acc[j]);
            ov[j] = (short)f2bf(s);
        }
        *(bf16x8*)&xc16[(size_t)(bl0 + t) * DI_ + d] = ov;
    }
}

// pass1: chunk-local end state (zero init) + sum(delta); delta bf16.
// Timestep loop unrolled x4 with batched loads: 8 independent scalar loads
// issued ahead of 4 compute blocks -> load latency hides under ~400 cyc of
// VALU (the per-thread chain is otherwise serial: load->bf2f->exp2->fma).
__global__ __launch_bounds__(256) void scan_part1(
    const unsigned short* __restrict__ dl16, const unsigned short* __restrict__ xc16,
    const float* __restrict__ xdbl,
    const void* __restrict__ A_log, size_t aoff,
    float* __restrict__ sumdbuf, float* __restrict__ scrS,
    const int* __restrict__ flags, int layer)
{
    int isbf = flags[0], fast = flags[1 + layer];
    __shared__ float bs[LC_][16];
    int c = blockIdx.y;
    int b = blockIdx.x >> 3;
    int d = ((blockIdx.x & 7) << 8) + threadIdx.x;
    for (int i = threadIdx.x; i < LC_ * 16; i += 256) {
        int l = i >> 4, n = i & 15;
        bs[l][n] = xdbl[((size_t)b * L_ + c * LC_ + l) * NXD_ + DTR_ + n];
    }
    __syncthreads();
    float a2[16];
#pragma unroll
    for (int n = 0; n < 16; ++n)
        a2[n] = -expf_(ldin(A_log, aoff + (size_t)d * DS_ + n, isbf)) * LOG2E_;
    float s[16] = {};
    float sumd = 0.f;
    const unsigned short* dp = dl16 + ((size_t)b * L_ + c * LC_) * DI_ + d;
    const unsigned short* up = xc16 + ((size_t)b * L_ + c * LC_) * DI_ + d;
    for (int l0 = 0; l0 < LC_; l0 += 4) {
        float dvv[4], uv[4];
#pragma unroll
        for (int q = 0; q < 4; ++q) {
            dvv[q] = bf2f(dp[(size_t)(l0 + q) * DI_]);
            uv[q]  = bf2f(up[(size_t)(l0 + q) * DI_]);
        }
#pragma unroll
        for (int q = 0; q < 4; ++q) {
            int l = l0 + q;
            float dv = dvv[q];
            sumd += dv;
            float dvu = dv * uv[q];
            float e[16];
            expvec(fast, dv, a2, e);
            float4 b0 = *(const float4*)&bs[l][0];
            float4 b1 = *(const float4*)&bs[l][4];
            float4 b2 = *(const float4*)&bs[l][8];
            float4 b3 = *(const float4*)&bs[l][12];
            float bv[16] = {b0.x,b0.y,b0.z,b0.w, b1.x,b1.y,b1.z,b1.w,
                            b2.x,b2.y,b2.z,b2.w, b3.x,b3.y,b3.z,b3.w};
#pragma unroll
            for (int n = 0; n < 16; ++n)
                s[n] = fmaf(e[n], s[n], dvu * bv[n]);
        }
    }
    int g = b * DI_ + d;
    sumdbuf[(size_t)c * (B_ * DI_) + g] = sumd;
    size_t base = ((size_t)c * (B_ * DI_) + g) * 16;
#pragma unroll
    for (int q = 0; q < 4; ++q)
        *(float4*)&scrS[base + q * 4] =
            make_float4(s[q*4], s[q*4+1], s[q*4+2], s[q*4+3]);
}

// sequential combine: scrS[c] becomes the state ENTERING chunk c.
__global__ __launch_bounds__(256) void scan_combine(
    const float* __restrict__ sumdbuf, float* __restrict__ scrS,
    const void* __restrict__ A_log, size_t aoff, const int* __restrict__ flags)
{
    int isbf = flags[0];
    int t = blockIdx.x * 256 + threadIdx.x;    // g*16+n
    int g = t >> 4, n = t & 15;
    int d = g & (DI_ - 1);
    float a2 = -expf_(ldin(A_log, aoff + (size_t)d * DS_ + n, isbf)) * LOG2E_;
    float sd[NCH_], sl[NCH_];
#pragma unroll
    for (int c = 0; c < NCH_; ++c) {
        sd[c] = sumdbuf[(size_t)c * (B_ * DI_) + g];
        sl[c] = scrS[(size_t)c * (B_ * DI_ * 16) + t];
    }
    float s = 0.f;
#pragma unroll
    for (int c = 0; c < NCH_; ++c) {
        float P = __builtin_amdgcn_exp2f(a2 * sd[c]);
        float nxt = fmaf(P, s, sl[c]);
        scrS[(size_t)c * (B_ * DI_ * 16) + t] = s;
        s = nxt;
    }
}

// pass2: re-run chunk with correct init; y (bf16) written in place into xc16.
// Same x4 unroll + batched loads as pass1 (12 loads per group).
__global__ __launch_bounds__(256) void scan_part2(
    const unsigned short* __restrict__ dl16, unsigned short* __restrict__ xc16,
    const float* __restrict__ xdbl, const unsigned short* __restrict__ z,
    const void* __restrict__ A_log, size_t aoff,
    const void* __restrict__ Dskip, size_t doff,
    const float* __restrict__ scrS, const int* __restrict__ flags, int layer)
{
    int isbf = flags[0], fast = flags[1 + layer];
    __shared__ float bs[LC_][32];              // [l][n]=B, [l][16+n]=C
    int c = blockIdx.y;
    int b = blockIdx.x >> 3;
    int d = ((blockIdx.x & 7) << 8) + threadIdx.x;
    for (int i = threadIdx.x; i < LC_ * 32; i += 256) {
        int l = i >> 5, n = i & 31;
        bs[l][n] = xdbl[((size_t)b * L_ + c * LC_ + l) * NXD_ + DTR_ + n];
    }
    __syncthreads();
    float a2[16];
#pragma unroll
    for (int n = 0; n < 16; ++n)
        a2[n] = -expf_(ldin(A_log, aoff + (size_t)d * DS_ + n, isbf)) * LOG2E_;
    float Dv = ldin(Dskip, doff + d, isbf);
    int g = b * DI_ + d;
    size_t sbase = ((size_t)c * (B_ * DI_) + g) * 16;
    float s[16];
#pragma unroll
    for (int q = 0; q < 4; ++q) {
        float4 sv = *(const float4*)&scrS[sbase + q * 4];
        s[q*4] = sv.x; s[q*4+1] = sv.y; s[q*4+2] = sv.z; s[q*4+3] = sv.w;
    }

    const unsigned short* dp = dl16 + ((size_t)b * L_ + c * LC_) * DI_ + d;
    unsigned short* up = xc16 + ((size_t)b * L_ + c * LC_) * DI_ + d;
    const unsigned short* zp = z + ((size_t)b * L_ + c * LC_) * DI_ + d;
    for (int l0 = 0; l0 < LC_; l0 += 4) {
        float dvv[4], uv[4], zv[4];
#pragma unroll
        for (int q = 0; q < 4; ++q) {
            dvv[q] = bf2f(dp[(size_t)(l0 + q) * DI_]);
            uv[q]  = bf2f(up[(size_t)(l0 + q) * DI_]);
            zv[q]  = bf2f(zp[(size_t)(l0 + q) * DI_]);
        }
#pragma unroll
        for (int q = 0; q < 4; ++q) {
            int l = l0 + q;
            float dv = dvv[q], u = uv[q];
            float dvu = dv * u;
            float e[16];
            expvec(fast, dv, a2, e);
            float4 b0 = *(const float4*)&bs[l][0];
            float4 b1 = *(const float4*)&bs[l][4];
            float4 b2 = *(const float4*)&bs[l][8];
            float4 b3 = *(const float4*)&bs[l][12];
            float4 c0 = *(const float4*)&bs[l][16];
            float4 c1 = *(const float4*)&bs[l][20];
            float4 c2 = *(const float4*)&bs[l][24];
            float4 c3 = *(const float4*)&bs[l][28];
            float bv[16] = {b0.x,b0.y,b0.z,b0.w, b1.x,b1.y,b1.z,b1.w,
                            b2.x,b2.y,b2.z,b2.w, b3.x,b3.y,b3.z,b3.w};
            float cv[16] = {c0.x,c0.y,c0.z,c0.w, c1.x,c1.y,c1.z,c1.w,
                            c2.x,c2.y,c2.z,c2.w, c3.x,c3.y,c3.z,c3.w};
            float y = 0.f;
#pragma unroll
            for (int n = 0; n < 16; ++n) {
                s[n] = fmaf(e[n], s[n], dvu * bv[n]);
                y = fmaf(s[n], cv[n], y);
            }
            float zvv = zv[q];
            up[(size_t)l * DI_] = f2bf((y + u * Dv) * (zvv * sigmoidf_(zvv)));
        }
    }
}

// h = rmsnorm(y0 + y1 + h) * norm_w ; also bf16 copy; optionally final out
__global__ __launch_bounds__(256) void rmsnorm_kernel(
    const float* __restrict__ y0, const float* __restrict__ y1,
    float* __restrict__ h, unsigned short* __restrict__ h16,
    const void* __restrict__ nw, size_t nwoff, void* __restrict__ out,
    int write_out, const int* __restrict__ flag)
{
    int isbf = *flag;
    __shared__ float red[4];
    int row = blockIdx.x;
    float* hp = h + (size_t)row * E_;
    float v[4]; float ss = 0.f;
#pragma unroll
    for (int i = 0; i < 4; ++i) {
        int e = threadIdx.x + i * 256;
        size_t idx = (size_t)row * E_ + e;
        v[i] = y0[idx] + y1[idx] + hp[e];
        ss += v[i] * v[i];
    }
#pragma unroll
    for (int off = 1; off < 64; off <<= 1) ss += __shfl_xor(ss, off, 64);
    if ((threadIdx.x & 63) == 0) red[threadIdx.x >> 6] = ss;
    __syncthreads();
    ss = red[0] + red[1] + red[2] + red[3];
    float scale = rsqrtf(ss * (1.f / E_) + 1e-6f);
#pragma unroll
    for (int i = 0; i < 4; ++i) {
        int e = threadIdx.x + i * 256;
        float hv = v[i] * scale * ldin(nw, nwoff + e, isbf);
        hp[e] = hv;
        h16[(size_t)row * E_ + e] = f2bf(hv);
        if (write_out) {
            size_t oi = (size_t)row * E_ + e;
            if (isbf) ((unsigned short*)out)[oi] = f2bf(hv);
            else      ((float*)out)[oi] = hv;
        }
    }
}

extern "C" void kernel_launch(void* const* d_in, const int* in_sizes, int n_in,
                              void* d_out, int out_size, void* d_ws, size_t ws_size,
                              hipStream_t stream)
{
    const void* x    = d_in[0];
    const void* pos  = d_in[1];
    const void* inw  = d_in[2];
    const void* cw   = d_in[3];
    const void* cb   = d_in[4];
    const void* xw   = d_in[5];
    const void* dtw  = d_in[6];
    const void* dtb  = d_in[7];
    const void* alog = d_in[8];
    const void* dsk  = d_in[9];
    const void* ow   = d_in[10];
    const void* nw   = d_in[11];

    float* ws = (float*)d_ws;
    float* h      = ws;                                        // 4,194,304 f
    unsigned short* h16  = (unsigned short*)(ws + 4194304);    // 2,097,152 f
    unsigned short* z16  = (unsigned short*)(ws + 6291456);    // 4,194,304 f
    unsigned short* xc16 = (unsigned short*)(ws + 10485760);   // 4,194,304 f
    float* D      = ws + 14680064;                             // 8,388,608 f (delta16 -> yout x2)
    float* R      = ws + 23068672;                             // 4,194,304 f (xcr16/xp_part/scrS)
    float* xdbl   = ws + 27262976;                             //   393,216 f
    unsigned short* dt16 = (unsigned short*)(ws + 27656192);   //   131,072 f
    float* sumd   = ws + 27787264;                             //   262,144 f
    unsigned short* wbuf = (unsigned short*)(ws + 28049408);   // 3,342,336 f
    int* flags    = (int*)(ws + 31391744);
    // total ~125.6 MB (same proven footprint)

    unsigned short* xcr16 = (unsigned short*)R;    // in_proj xc_raw (bf16)
    float* xp_part = R;                            // x_proj split-K partials
    float* scrS    = R;                            // scan chunk states (16.8 MB)
    unsigned short* dl16 = (unsigned short*)D;     // delta bf16 (dead before yout)
    float* yout0 = D;
    float* yout1 = D + (size_t)M_ * E_;
    // conv weight transpose lives in sumd (dead until scan_part1)
    float* cwT = sumd;                             // DC_*DI_ = 8192 f
    float* cbF = sumd + DC_ * DI_;                 // DI_ = 2048 f

    detect_kernel<<<1, 256, 0, stream>>>((const unsigned*)x, flags);
    chk_alog<<<NL_ * DI_ * DS_ / 256, 256, 0, stream>>>(alog, flags);
    add_pos_kernel<<<M_ * E_ / 256, 256, 0, stream>>>(x, pos, h, h16, flags);

    for (int layer = 0; layer < NL_; ++layer) {
        const unsigned short* inws = (const unsigned short*)inw + (size_t)layer * 2 * DI_ * E_;
        const unsigned short* dtws = (const unsigned short*)dtw + (size_t)layer * DI_ * DTR_;
        const unsigned short* ows  = (const unsigned short*)ow  + (size_t)layer * E_ * DI_;

        cvt_layer_kernel<<<WB_TOT_ / 256, 256, 0, stream>>>(
            inw, xw, dtw, ow, layer, wbuf, flags);
        conv_prep<<<DI_ / 256, 256, 0, stream>>>(
            cw, (size_t)layer * DI_ * DC_, cb, (size_t)layer * DI_, cwT, cbF, flags);

        // fused in_proj: [xc_raw | z] = h @ in_proj^T  (256x256 8-phase)
        gemm_inproj8<<<dim3(M_ / 256, 2 * DI_ / 256, 1), 512, 0, stream>>>(
            h16, wbuf + WB_IN_, inws, flags, xcr16, z16);
        // xc = silu(conv(xc_raw)+cb), vectorized 8ch x 4t per thread
        conv_silu_v<<<M_ / CT_, 256, 0, stream>>>(xcr16, cwT, cbF, xc16);
        // x_dbl partials: split-K=8 (256 blocks), then reduce -> xdbl + dt16
        gemm_mfma<<<dim3(M_ / 128, 1, 8), 256, 0, stream>>>(
            xc16, DI_, wbuf + WB_XW_, DI_, xp_part, 128, DI_ / 8, (size_t)M_ * 128,
            nullptr, 0, nullptr, 0, flags, nullptr);
        xproj_reduce<<<M_ * 128 / 256, 256, 0, stream>>>(xp_part, xdbl, dt16);
        // delta = softplus(dt @ dt_proj^T + dtb) -> dl16 (bf16)
        gemm_mfma<<<dim3(M_ / 128, DI_ / 128, 1), 256, 0, stream>>>(
            dt16, DTR_, wbuf + WB_DTW_, DTR_, dl16, DI_, DTR_, 0,
            dtb, (size_t)layer * DI_, nullptr, 2, flags, dtws);
        // chunked scan (16-state + x4 load batching); y in place into xc16
        scan_part1<<<dim3(B_ * DI_ / 256, NCH_), 256, 0, stream>>>(
            dl16, xc16, xdbl, alog, (size_t)layer * DI_ * DS_, sumd, scrS, flags, layer);
        scan_combine<<<B_ * DI_ * DS_ / 256, 256, 0, stream>>>(
            sumd, scrS, alog, (size_t)layer * DI_ * DS_, flags);
        scan_part2<<<dim3(B_ * DI_ / 256, NCH_), 256, 0, stream>>>(
            dl16, xc16, xdbl, z16, alog, (size_t)layer * DI_ * DS_,
            dsk, (size_t)layer * DI_, scrS, flags, layer);
        // yout = y @ out_proj^T, split-K=2 (512 blocks) -> yout partials
        gemm_mfma<<<dim3(M_ / 128, E_ / 128, 2), 256, 0, stream>>>(
            xc16, DI_, wbuf + WB_OW_, DI_, yout0, E_, DI_ / 2, (size_t)M_ * E_,
            nullptr, 0, nullptr, 0, flags, ows);
        // h = rmsnorm(yout0 + yout1 + h); emit output on last layer
        rmsnorm_kernel<<<M_, 256, 0, stream>>>(
            yout0, yout1, h, h16, nw, (size_t)layer * E_, d_out,
            layer == NL_ - 1 ? 1 : 0, flags);
    }
}